// Round 1
// 308.365 us; speedup vs baseline: 1.0570x; 1.0570x over previous
//
#include <hip/hip_runtime.h>
#include <hip/hip_bf16.h>
#include <math.h>

#define B_ 2
#define S_ 2048
#define D_ 2048
#define NH_ 16
#define NKV_ 4
#define HD_ 128
#define EPS_ 1e-6f
#define SCALE_ 0.08838834764831845f  // 1/sqrt(128)
#define LOG2E_ 1.4426950408889634f
#define KOFF_ 2048                   // k rows offset in fused Wt
#define VOFF_ 2560                   // v rows offset in fused Wt

typedef float f32x4 __attribute__((ext_vector_type(4)));
typedef short bf16x8 __attribute__((ext_vector_type(8)));
typedef short short4v __attribute__((ext_vector_type(4)));
typedef float float4v __attribute__((ext_vector_type(4)));
typedef unsigned uint2v __attribute__((ext_vector_type(2)));
typedef unsigned uint4v __attribute__((ext_vector_type(4)));

static __device__ __forceinline__ short f2bf(float f) {
    union { float f; unsigned u; } x{f};
    unsigned r = (x.u + 0x7fff + ((x.u >> 16) & 1)) >> 16;   // RTNE
    return (short)r;
}
static __device__ __forceinline__ float bf2f(short s) {
    union { unsigned u; float f; } x; x.u = ((unsigned)(unsigned short)s) << 16; return x.f;
}
// pack two fp32 -> two bf16 (truncation) in ONE v_perm: lo16=hi16(a), hi16=hi16(b)
static __device__ __forceinline__ unsigned pack_bf2(float a, float b) {
    return __builtin_amdgcn_perm(__builtin_bit_cast(unsigned, b),
                                 __builtin_bit_cast(unsigned, a), 0x07060302u);
}

#define AS1(p) ((const __attribute__((address_space(1))) void*)(p))
#define AS3(p) ((__attribute__((address_space(3))) void*)(p))
static __device__ __forceinline__ void async16(const void* g, void* l) {
    __builtin_amdgcn_global_load_lds(AS1(g), AS3(l), 16, 0, 0);
}

// ---------------------------------------------------------------------------
// fp32 -> bf16 flat cast (for x). 4 elems/thread.
// ---------------------------------------------------------------------------
__global__ __launch_bounds__(256) void cast_kernel(const float* __restrict__ in,
                                                   short* __restrict__ out) {
    size_t i = ((size_t)blockIdx.x * 256 + threadIdx.x) * 4;
    float4v v = *(const float4v*)(in + i);
    short4v o; o.x = f2bf(v.x); o.y = f2bf(v.y); o.z = f2bf(v.z); o.w = f2bf(v.w);
    *(short4v*)(out + i) = o;
}

// ---------------------------------------------------------------------------
// All 4 weight transposes in ONE launch. fp32 [K=2048][N] -> bf16 [N][2048].
// grid (80, 32): bx<32 Wq | <40 Wk | <48 Wv | else Wo.
// ---------------------------------------------------------------------------
__global__ __launch_bounds__(256) void transpose_all_kernel(const float* __restrict__ Wq,
                                                            const float* __restrict__ Wk,
                                                            const float* __restrict__ Wv,
                                                            const float* __restrict__ Wo,
                                                            short* __restrict__ Wt,
                                                            short* __restrict__ Wot) {
    __shared__ float tile[64][65];
    const int bx = blockIdx.x, by = blockIdx.y;
    const float* src; short* dst; int N, nb;
    if (bx < 32)      { src = Wq; dst = Wt;                         N = 2048; nb = bx; }
    else if (bx < 40) { src = Wk; dst = Wt + (size_t)KOFF_ * 2048;  N = 512;  nb = bx - 32; }
    else if (bx < 48) { src = Wv; dst = Wt + (size_t)VOFF_ * 2048;  N = 512;  nb = bx - 40; }
    else              { src = Wo; dst = Wot;                        N = 2048; nb = bx - 48; }
    const int n0 = nb * 64, k0 = by * 64;
    const int tid = threadIdx.x;
    for (int r = 0; r < 16; ++r) {
        int k = r * 4 + (tid >> 6);
        int n = tid & 63;
        tile[k][n] = src[(size_t)(k0 + k) * N + n0 + n];
    }
    __syncthreads();
    for (int r = 0; r < 4; ++r) {
        int n  = r * 16 + (tid >> 4);
        int kk = (tid & 15) * 4;
        short4v o4;
        o4.x = f2bf(tile[kk + 0][n]); o4.y = f2bf(tile[kk + 1][n]);
        o4.z = f2bf(tile[kk + 2][n]); o4.w = f2bf(tile[kk + 3][n]);
        *(short4v*)&dst[(size_t)(n0 + n) * 2048 + k0 + kk] = o4;
    }
}

// ---------------------------------------------------------------------------
// m97-style GEMM (used for O-proj): C[M][N] = A[M][K] @ Bt[N][K]^T, fp32 out.
// ---------------------------------------------------------------------------
template<typename TC>
__global__ __launch_bounds__(256) void gemm_tt_kernel(const short* __restrict__ A,
                                                      const short* __restrict__ Bt,
                                                      TC* __restrict__ C,
                                                      int M, int N, int K) {
    __shared__ short As[128 * 32];
    __shared__ short Bs[128 * 32];

    const int tid  = threadIdx.x;
    const int bn   = blockIdx.x, bm = blockIdx.y;
    const int wave = tid >> 6, lane = tid & 63;
    const int quad = lane >> 4, l16 = lane & 15;
    const int wr = wave >> 1, wc = wave & 1;

    f32x4 acc[4][4];
    for (int i = 0; i < 4; ++i)
        for (int j = 0; j < 4; ++j) acc[i][j] = (f32x4){0.f, 0.f, 0.f, 0.f};

    const short* Abase = A  + (size_t)(bm * 128) * K;
    const short* Bbase = Bt + (size_t)(bn * 128) * K;

    int ci0 = wave * 128 + lane;
    for (int k0 = 0; k0 < K; k0 += 32) {
        __syncthreads();
        for (int t = 0; t < 2; ++t) {
            int ci = ci0 + t * 64;
            int r  = ci >> 2;
            int c  = ((ci & 3) - (r >> 1)) & 3;
            size_t goff = (size_t)r * K + k0 + c * 8;
            async16(Abase + goff, &As[ci * 8]);
            async16(Bbase + goff, &Bs[ci * 8]);
        }
        __syncthreads();

        bf16x8 af[4], bfv[4];
        for (int mt = 0; mt < 4; ++mt) {
            int r = wr * 64 + mt * 16 + l16;
            af[mt] = *(const bf16x8*)&As[r * 32 + (((quad + (r >> 1)) & 3) * 8)];
        }
        for (int nt = 0; nt < 4; ++nt) {
            int r = wc * 64 + nt * 16 + l16;
            bfv[nt] = *(const bf16x8*)&Bs[r * 32 + (((quad + (r >> 1)) & 3) * 8)];
        }
        for (int mt = 0; mt < 4; ++mt)
            for (int nt = 0; nt < 4; ++nt)
                acc[mt][nt] = __builtin_amdgcn_mfma_f32_16x16x32_bf16(
                    af[mt], bfv[nt], acc[mt][nt], 0, 0, 0);
    }

    for (int mt = 0; mt < 4; ++mt)
        for (int nt = 0; nt < 4; ++nt)
            for (int j = 0; j < 4; ++j) {
                int row = bm * 128 + wr * 64 + mt * 16 + quad * 4 + j;
                int col = bn * 128 + wc * 64 + nt * 16 + l16;
                float v = acc[mt][nt][j];
                if constexpr (__is_same(TC, short))
                    C[(size_t)row * N + col] = f2bf(v);
                else
                    C[(size_t)row * N + col] = v;
            }
}

// ---------------------------------------------------------------------------
// Fused QKV GEMM + RMSNorm + RoPE + V-transpose — 256x256 8-phase schedule.
// C = xb[4096][2048] @ Wt[3072][2048]^T, tile 256x256, BK=64, 512 thr (8 waves
// as 2Mx4N, each wave owns a 128x64 sub-tile). grid (12, 16).
// bn<8 : Q heads 2*bn,2*bn+1 -> q_rope (b,s,h,hd), RMS+RoPE, scaled.
// bn<10: K heads -> k_rope (b,g,s,hd), RMS+RoPE.
// else : V heads -> vt (b,g,d,s), raw bf16 direct stores.
//
// LDS: A/B double-buffered [2][256][64] bf16 = 128KB, XOR-swizzled reads
// (colbyte ^= (row&7)<<4), linear global_load_lds dest with inverse-swizzled
// global source. Staging: 1 half-tile (128 rows) per phase, issued 4-6 phases
// ahead; vmcnt(4) only at phases 4/8 (drain-to-0 only on the peeled last iter).
// After the loop the 128KB staging LDS is reused as the 256x256 bf16 C tile
// for the RMSNorm+RoPE epilogue.
// ---------------------------------------------------------------------------
#define QKV_ITERS 16   // K=2048 / (2 K-tiles * 64)

__global__ __launch_bounds__(512, 2) void qkv_fused_kernel(const short* __restrict__ xb,
                                                           const short* __restrict__ Wt,
                                                           const float* __restrict__ cosb,
                                                           const float* __restrict__ sinb,
                                                           const float* __restrict__ qw,
                                                           const float* __restrict__ kw,
                                                           short* __restrict__ q_rope,
                                                           short* __restrict__ k_rope,
                                                           short* __restrict__ vtr) {
    __shared__ __align__(16) short smem[65536];   // 128KB: A0|A1|B0|B1, then C tile
    __shared__ float ss2[4][256];                 // per-row sumsq per wc group

    short* A0 = smem;
    short* A1 = smem + 16384;
    short* B0 = smem + 32768;
    short* B1 = smem + 49152;

    const int tid  = threadIdx.x;
    const int bn   = blockIdx.x, bm = blockIdx.y;
    const int wave = tid >> 6, lane = tid & 63;
    const int quad = lane >> 4, l16 = lane & 15;
    const int wr = wave >> 2, wc = wave & 3;      // 2M x 4N waves

    const short* Ag = xb + (size_t)(bm * 256) * 2048;
    const short* Bg = Wt + (size_t)(bn * 256) * 2048;

    f32x4 acc[8][4];
#pragma unroll
    for (int i = 0; i < 8; ++i)
#pragma unroll
        for (int j = 0; j < 4; ++j) acc[i][j] = (f32x4){0.f, 0.f, 0.f, 0.f};

    bf16x8 a[4][2], b0[2][2], b1[2][2];

    // stage one half-tile (128 rows x 64 k) of a 256x64 slot; LDS dest linear,
    // global source inverse-swizzled so swizzled ds_reads return true data.
    auto stage_half = [&](const short* gpanel, int t, int h, short* lslot) {
#pragma unroll
        for (int u = 0; u < 2; ++u) {
            int ci = u * 512 + tid;                 // 0..1023
            int r  = ci >> 3;                       // 0..127
            int cb = ((ci & 7) * 16) ^ ((r & 7) << 4);
            async16(gpanel + (size_t)(h * 128 + r) * 2048 + t * 64 + (cb >> 1),
                    lslot + h * 8192 + ci * 8);
        }
    };

#define LDA_(lbuf, qm) \
    _Pragma("unroll") for (int mt = 0; mt < 4; ++mt) \
    _Pragma("unroll") for (int ks = 0; ks < 2; ++ks) { \
        int row_ = wr * 128 + (qm) * 64 + mt * 16 + l16; \
        int cb_  = (ks * 64 + quad * 16) ^ ((row_ & 7) << 4); \
        a[mt][ks] = *(const bf16x8*)&(lbuf)[row_ * 64 + (cb_ >> 1)]; \
    }
#define LDB_(lbuf, qn, breg) \
    _Pragma("unroll") for (int ntl = 0; ntl < 2; ++ntl) \
    _Pragma("unroll") for (int ks = 0; ks < 2; ++ks) { \
        int row_ = wc * 64 + (qn) * 32 + ntl * 16 + l16; \
        int cb_  = (ks * 64 + quad * 16) ^ ((row_ & 7) << 4); \
        breg[ntl][ks] = *(const bf16x8*)&(lbuf)[row_ * 64 + (cb_ >> 1)]; \
    }
#define MFMA16_(qm, qn, breg) \
    _Pragma("unroll") for (int mt = 0; mt < 4; ++mt) \
    _Pragma("unroll") for (int ntl = 0; ntl < 2; ++ntl) \
    _Pragma("unroll") for (int ks = 0; ks < 2; ++ks) \
        acc[(qm) * 4 + mt][(qn) * 2 + ntl] = __builtin_amdgcn_mfma_f32_16x16x32_bf16( \
            a[mt][ks], breg[ntl][ks], acc[(qm) * 4 + mt][(qn) * 2 + ntl], 0, 0, 0);
#define PH_BAR() do { __builtin_amdgcn_sched_barrier(0); __builtin_amdgcn_s_barrier(); } while (0)
#define PH_MFMA(qm, qn, breg) do { \
        __builtin_amdgcn_s_setprio(1); MFMA16_(qm, qn, breg); __builtin_amdgcn_s_setprio(0); \
        __builtin_amdgcn_sched_barrier(0); __builtin_amdgcn_s_barrier(); } while (0)

    // prologue: B(0), A(0), B(1); drain first two tiles, keep B(1) in flight
    stage_half(Bg, 0, 0, B0); stage_half(Bg, 0, 1, B0);
    stage_half(Ag, 0, 0, A0); stage_half(Ag, 0, 1, A0);
    stage_half(Bg, 1, 0, B1); stage_half(Bg, 1, 1, B1);
    asm volatile("s_waitcnt vmcnt(4)" ::: "memory");
    __builtin_amdgcn_s_barrier();

#pragma unroll 1
    for (int i = 0; i < QKV_ITERS; ++i) {
        const int tE = 2 * i, tO = 2 * i + 1;
        const bool more = (i < QKV_ITERS - 1);
        // ---- phases 1-4: tile tE from buf0 ----
        LDA_(A0, 0); LDB_(B0, 0, b0);
        stage_half(Ag, tO, 0, A1);
        PH_BAR(); PH_MFMA(0, 0, b0);

        LDB_(B0, 1, b1);
        stage_half(Ag, tO, 1, A1);
        PH_BAR(); PH_MFMA(0, 1, b1);

        LDA_(A0, 1);
        if (more) stage_half(Bg, tE + 2, 0, B0);
        PH_BAR(); PH_MFMA(1, 0, b0);

        if (more) {
            stage_half(Bg, tE + 2, 1, B0);
            asm volatile("s_waitcnt vmcnt(4)" ::: "memory");
        } else {
            asm volatile("s_waitcnt vmcnt(0)" ::: "memory");
        }
        PH_BAR(); PH_MFMA(1, 1, b1);

        // ---- phases 5-8: tile tO from buf1 ----
        LDA_(A1, 0); LDB_(B1, 0, b0);
        if (more) stage_half(Ag, tE + 2, 0, A0);
        PH_BAR(); PH_MFMA(0, 0, b0);

        LDB_(B1, 1, b1);
        if (more) stage_half(Ag, tE + 2, 1, A0);
        PH_BAR(); PH_MFMA(0, 1, b1);

        LDA_(A1, 1);
        if (more) stage_half(Bg, tO + 2, 0, B1);
        PH_BAR(); PH_MFMA(1, 0, b0);

        if (more) {
            stage_half(Bg, tO + 2, 1, B1);
            asm volatile("s_waitcnt vmcnt(4)" ::: "memory");
        } else {
            asm volatile("s_waitcnt vmcnt(0)" ::: "memory");
        }
        PH_BAR(); PH_MFMA(1, 1, b1);
    }

    // ----------------------- epilogue -----------------------
    if (bn >= 10) {
        // V: direct transposed store, (b,g,d,s), 4-token runs of 8B
        const int gbase = (bn - 10) * 2;
#pragma unroll
        for (int am = 0; am < 8; ++am) {
            int tok0 = bm * 256 + wr * 128 + am * 16 + quad * 4;
            int bb = tok0 >> 11, s0 = tok0 & (S_ - 1);
#pragma unroll
            for (int nt = 0; nt < 4; ++nt) {
                int col = wc * 64 + nt * 16 + l16;
                int g = gbase + (col >> 7);
                int d = col & 127;
                short4v o4;
                o4.x = f2bf(acc[am][nt][0]); o4.y = f2bf(acc[am][nt][1]);
                o4.z = f2bf(acc[am][nt][2]); o4.w = f2bf(acc[am][nt][3]);
                *(short4v*)&vtr[((size_t)(bb * NKV_ + g) * HD_ + d) * S_ + s0] = o4;
            }
        }
        return;
    }

    // Q/K: per-row sumsq (per 64-col wave group) + bf16 C tile into LDS
    {
        float pss[8][4];
#pragma unroll
        for (int am = 0; am < 8; ++am)
#pragma unroll
            for (int j = 0; j < 4; ++j) {
                float s = 0.f;
#pragma unroll
                for (int nt = 0; nt < 4; ++nt) s += acc[am][nt][j] * acc[am][nt][j];
                pss[am][j] = s;
            }
#pragma unroll
        for (int off = 1; off < 16; off <<= 1)
#pragma unroll
            for (int am = 0; am < 8; ++am)
#pragma unroll
                for (int j = 0; j < 4; ++j)
                    pss[am][j] += __shfl_xor(pss[am][j], off);
        if (l16 == 0)
#pragma unroll
            for (int am = 0; am < 8; ++am)
#pragma unroll
                for (int j = 0; j < 4; ++j)
                    ss2[wc][wr * 128 + am * 16 + quad * 4 + j] = pss[am][j];
    }
    short* ct = smem;   // 256x256 bf16 C tile (overlays staging buffers)
#pragma unroll
    for (int am = 0; am < 8; ++am)
#pragma unroll
        for (int nt = 0; nt < 4; ++nt)
#pragma unroll
            for (int j = 0; j < 4; ++j)
                ct[(wr * 128 + am * 16 + quad * 4 + j) * 256 + wc * 64 + nt * 16 + l16]
                    = f2bf(acc[am][nt][j]);
    __syncthreads();

    const bool isQ = (bn < 8);
    const float osc = isQ ? (SCALE_ * LOG2E_) : 1.0f;
    const float* w = isQ ? qw : kw;
#pragma unroll 1
    for (int it = 0; it < 16; ++it) {
        int idx = it * 512 + tid;          // 0..8191
        int row = idx >> 5;
        int s32 = idx & 31;
        int head = s32 >> 4, seg = s32 & 15;
        int tok = bm * 256 + row;
        int bb = tok >> 11, s = tok & (S_ - 1);
        float rstd = rsqrtf((ss2[2 * head][row] + ss2[2 * head + 1][row]) * (1.0f / HD_) + EPS_);
        int c0 = seg * 8, p0 = (seg ^ 8) * 8;
        bf16x8 ta = *(const bf16x8*)&ct[row * 256 + head * 128 + c0];
        bf16x8 tb = *(const bf16x8*)&ct[row * 256 + head * 128 + p0];
        float sgn = (seg < 8) ? -1.0f : 1.0f;
        float4v cs0 = *(const float4v*)&cosb[(size_t)s * HD_ + c0];
        float4v cs1 = *(const float4v*)&cosb[(size_t)s * HD_ + c0 + 4];
        float4v sn0 = *(const float4v*)&sinb[(size_t)s * HD_ + c0];
        float4v sn1 = *(const float4v*)&sinb[(size_t)s * HD_ + c0 + 4];
        float ov[8];
#pragma unroll
        for (int i = 0; i < 8; ++i) {
            float n1 = bf2f(ta[i]) * rstd * w[c0 + i];
            float n2 = bf2f(tb[i]) * rstd * w[p0 + i];
            float cs = (i < 4) ? cs0[i & 3] : cs1[i & 3];
            float sn = (i < 4) ? sn0[i & 3] : sn1[i & 3];
            ov[i] = (n1 * cs + sgn * n2 * sn) * osc;
        }
        uint4v wv;
#pragma unroll
        for (int i2 = 0; i2 < 4; ++i2)
            wv[i2] = ((unsigned)(unsigned short)f2bf(ov[2 * i2])) |
                     ((unsigned)(unsigned short)f2bf(ov[2 * i2 + 1]) << 16);
        int gh = isQ ? (bn * 2 + head) : ((bn - 8) * 2 + head);
        short* dst = isQ
            ? q_rope + ((size_t)(bb * S_ + s) * NH_ + gh) * HD_ + c0
            : k_rope + ((size_t)(bb * NKV_ + gh) * S_ + s) * HD_ + c0;
        *(uint4v*)dst = wv;
    }
#undef LDA_
#undef LDB_
#undef MFMA16_
#undef PH_BAR
#undef PH_MFMA
}

// ---------------------------------------------------------------------------
// Flash causal GQA attention v4 (unchanged).
// ---------------------------------------------------------------------------
__global__ __launch_bounds__(256, 2) void attn_kernel(const short* __restrict__ qr,
                                                      const short* __restrict__ kg,
                                                      const short* __restrict__ vt,
                                                      short* __restrict__ aout) {
    __shared__ short Ks[2][64 * 128];
    __shared__ short Vs[2][128 * 64];

    const int lin = blockIdx.x;
    const int b  = lin & 1;
    const int g  = (lin >> 1) & 3;
    const int hq = (lin >> 3) & 3;
    const int pr = lin >> 5;
    const int h  = g * 4 + hq;

    const int wave = threadIdx.x >> 6, lane = threadIdx.x & 63;
    const int quad = lane >> 4, l16 = lane & 15;

    const short* kbase = kg + (size_t)(b * NKV_ + g) * S_ * HD_;
    const short* vbase = vt + (size_t)(b * NKV_ + g) * HD_ * S_;

    for (int pass = 0; pass < 2; ++pass) {
        const int qt    = pass ? (31 - pr) : pr;
        const int iters = qt + 1;
        const int qrow  = qt * 64 + wave * 16 + l16;

        bf16x8 qf[4];
        {
            const short* qp = qr + ((size_t)(b * S_ + qrow) * NH_ + h) * HD_;
            for (int ks = 0; ks < 4; ++ks)
                qf[ks] = *(const bf16x8*)(qp + ks * 32 + quad * 8);
        }

        f32x4 o[8];
        for (int i = 0; i < 8; ++i) o[i] = (f32x4){0.f, 0.f, 0.f, 0.f};
        float m_i = -INFINITY, l_i = 0.f;

        auto stage = [&](int kt, int bsel) {
            const short* kt_base = kbase + (size_t)kt * 64 * HD_;
            const short* vt_base = vbase + kt * 64;
            for (int t = 0; t < 4; ++t) {
                int ci  = (wave * 4 + t) * 64 + lane;
                int key = ci >> 4;
                int c   = (ci & 15) ^ ((key ^ (key >> 2)) & 15);
                async16(kt_base + key * HD_ + c * 8, &Ks[bsel][ci * 8]);
            }
            for (int t = 0; t < 4; ++t) {
                int ci = (wave * 4 + t) * 64 + lane;
                int d  = ci >> 3;
                int c  = (ci & 7) ^ (d & 7);
                async16(vt_base + (size_t)d * S_ + c * 8, &Vs[bsel][ci * 8]);
            }
        };

        stage(0, 0);
        int buf = 0;
        for (int kt = 0; kt < iters; ++kt) {
            __syncthreads();
            if (kt + 1 < iters) stage(kt + 1, buf ^ 1);

            f32x4 acc[4];
            for (int t = 0; t < 4; ++t) acc[t] = (f32x4){0.f, 0.f, 0.f, 0.f};
            for (int t = 0; t < 4; ++t) {
                int lk = ((t >> 1) << 5) + ((l16 >> 2) << 3) + ((t & 1) << 2) + (l16 & 3);
                const short* kp = &Ks[buf][lk * 128];
                int pm = (lk ^ (lk >> 2)) & 15;
                for (int ks = 0; ks < 4; ++ks) {
                    bf16x8 kf = *(const bf16x8*)(kp + (((ks * 4 + quad) ^ pm) * 8));
                    acc[t] = __builtin_amdgcn_mfma_f32_16x16x32_bf16(kf, qf[ks], acc[t], 0, 0, 0);
                }
            }
            const int key_base = kt * 64;
            if (key_base + 63 > qt * 64 + wave * 16) {
                for (int t = 0; t < 4; ++t)
                    for (int j = 0; j < 4; ++j) {
                        int kl = key_base + ((t >> 1) << 5) + (quad << 3) + ((t & 1) << 2) + j;
                        if (kl > qrow) acc[t][j] = -INFINITY;
                    }
            }
            float mx = m_i;
            for (int t = 0; t < 4; ++t)
                for (int j = 0; j < 4; ++j) mx = fmaxf(mx, acc[t][j]);
            mx = fmaxf(mx, __shfl_xor(mx, 16));
            mx = fmaxf(mx, __shfl_xor(mx, 32));
            float al = __builtin_amdgcn_exp2f(m_i - mx);
            m_i = mx;
            float rs = 0.f;
            float p[4][4];
            for (int t = 0; t < 4; ++t)
                for (int j = 0; j < 4; ++j) {
                    float e = __builtin_amdgcn_exp2f(acc[t][j] - mx);
                    p[t][j] = e;
                    rs += e;
                }
            rs += __shfl_xor(rs, 16);
            rs += __shfl_xor(rs, 32);
            l_i = al * l_i + rs;
            for (int d8 = 0; d8 < 8; ++d8)
                for (int j = 0; j < 4; ++j) o[d8][j] *= al;
            unsigned pk[2][4];
            for (int grp = 0; grp < 2; ++grp) {
                pk[grp][0] = pack_bf2(p[2 * grp][0],     p[2 * grp][1]);
                pk[grp][1] = pack_bf2(p[2 * grp][2],     p[2 * grp][3]);
                pk[grp][2] = pack_bf2(p[2 * grp + 1][0], p[2 * grp + 1][1]);
                pk[grp][3] = pack_bf2(p[2 * grp + 1][2], p[2 * grp + 1][3]);
            }
            for (int grp = 0; grp < 2; ++grp) {
                union { unsigned u[4]; bf16x8 v; } pb;
                for (int i = 0; i < 4; ++i) pb.u[i] = pk[grp][i];
                for (int d8 = 0; d8 < 8; ++d8) {
                    int d = d8 * 16 + l16;
                    bf16x8 vf = *(const bf16x8*)&Vs[buf][d * 64 + (((grp * 4 + quad) ^ (d & 7)) * 8)];
                    o[d8] = __builtin_amdgcn_mfma_f32_16x16x32_bf16(vf, pb.v, o[d8], 0, 0, 0);
                }
            }
            buf ^= 1;
        }
        float il = 1.0f / l_i;
        short* op = aout + ((size_t)(b * S_ + qrow) * NH_ + h) * HD_ + quad * 4;
        for (int d8 = 0; d8 < 8; ++d8) {
            uint2v wv;
            wv.x = ((unsigned)(unsigned short)f2bf(o[d8][0] * il)) |
                   ((unsigned)(unsigned short)f2bf(o[d8][1] * il) << 16);
            wv.y = ((unsigned)(unsigned short)f2bf(o[d8][2] * il)) |
                   ((unsigned)(unsigned short)f2bf(o[d8][3] * il) << 16);
            *(uint2v*)(op + d8 * 16) = wv;
        }
        __syncthreads();
    }
}

// ---------------------------------------------------------------------------
extern "C" void kernel_launch(void* const* d_in, const int* in_sizes, int n_in,
                              void* d_out, int out_size, void* d_ws, size_t ws_size,
                              hipStream_t stream) {
    (void)in_sizes; (void)n_in; (void)out_size; (void)ws_size;
    const float* x    = (const float*)d_in[0];
    const float* cosb = (const float*)d_in[1];
    const float* sinb = (const float*)d_in[2];
    const float* Wq   = (const float*)d_in[3];
    const float* Wk   = (const float*)d_in[4];
    const float* Wv   = (const float*)d_in[5];
    const float* Wo   = (const float*)d_in[6];
    const float* qw   = (const float*)d_in[7];
    const float* kw   = (const float*)d_in[8];
    float* out = (float*)d_out;

    char* ws = (char*)d_ws;
    short* xb     = (short*)ws;  ws += (size_t)4096 * 2048 * 2;    // 16MB
    short* Wt     = (short*)ws;  ws += (size_t)3072 * 2048 * 2;    // 12MB [n][k]
    short* Wot    = (short*)ws;  ws += (size_t)2048 * 2048 * 2;    // 8MB  [n][k]
    short* q_rope = (short*)ws;  ws += (size_t)4096 * 2048 * 2;    // 16MB (b,s,h,hd)
    short* k_rope = (short*)ws;  ws += (size_t)4096 * 512 * 2;     // 4MB  (b,g,s,hd)
    short* vt     = (short*)ws;  ws += (size_t)4096 * 512 * 2;     // 4MB  (b,g,hd,s)
    short* a_out  = (short*)ws;  ws += (size_t)4096 * 2048 * 2;    // 16MB

    const int M = B_ * S_;  // 4096

    // pre-pass: x cast + all weight transposes
    cast_kernel<<<M * 2048 / 1024, 256, 0, stream>>>(x, xb);
    transpose_all_kernel<<<dim3(80, 32), 256, 0, stream>>>(Wq, Wk, Wv, Wo, Wt, Wot);

    // fused QKV projection + RMSNorm + RoPE + V transpose (256^2 8-phase)
    qkv_fused_kernel<<<dim3(12, M / 256), 512, 0, stream>>>(
        xb, Wt, cosb, sinb, qw, kw, q_rope, k_rope, vt);

    // causal GQA flash attention: 512 equal blocks x 256 threads, 2 blocks/CU
    attn_kernel<<<512, 256, 0, stream>>>(q_rope, k_rope, vt, a_out);

    // output projection: [4096][2048] @ [2048][2048] -> fp32 out
    gemm_tt_kernel<float><<<dim3(D_ / 128, M / 128), 256, 0, stream>>>(
        a_out, Wot, out, M, D_, 2048);
}

// Round 2
// 307.267 us; speedup vs baseline: 1.0608x; 1.0036x over previous
//
#include <hip/hip_runtime.h>
#include <hip/hip_bf16.h>
#include <math.h>

#define B_ 2
#define S_ 2048
#define D_ 2048
#define NH_ 16
#define NKV_ 4
#define HD_ 128
#define EPS_ 1e-6f
#define SCALE_ 0.08838834764831845f  // 1/sqrt(128)
#define LOG2E_ 1.4426950408889634f
#define KOFF_ 2048                   // k rows offset in fused Wt
#define VOFF_ 2560                   // v rows offset in fused Wt

typedef float f32x4 __attribute__((ext_vector_type(4)));
typedef short bf16x8 __attribute__((ext_vector_type(8)));
typedef short short4v __attribute__((ext_vector_type(4)));
typedef float float4v __attribute__((ext_vector_type(4)));
typedef unsigned uint2v __attribute__((ext_vector_type(2)));
typedef unsigned uint4v __attribute__((ext_vector_type(4)));

static __device__ __forceinline__ short f2bf(float f) {
    union { float f; unsigned u; } x{f};
    unsigned r = (x.u + 0x7fff + ((x.u >> 16) & 1)) >> 16;   // RTNE
    return (short)r;
}
static __device__ __forceinline__ float bf2f(short s) {
    union { unsigned u; float f; } x; x.u = ((unsigned)(unsigned short)s) << 16; return x.f;
}
// pack two fp32 -> two bf16 (truncation) in ONE v_perm: lo16=hi16(a), hi16=hi16(b)
static __device__ __forceinline__ unsigned pack_bf2(float a, float b) {
    return __builtin_amdgcn_perm(__builtin_bit_cast(unsigned, b),
                                 __builtin_bit_cast(unsigned, a), 0x07060302u);
}

#define AS1(p) ((const __attribute__((address_space(1))) void*)(p))
#define AS3(p) ((__attribute__((address_space(3))) void*)(p))
static __device__ __forceinline__ void async16(const void* g, void* l) {
    __builtin_amdgcn_global_load_lds(AS1(g), AS3(l), 16, 0, 0);
}

// ---------------------------------------------------------------------------
// fp32 -> bf16 flat cast (for x). 4 elems/thread.
// ---------------------------------------------------------------------------
__global__ __launch_bounds__(256) void cast_kernel(const float* __restrict__ in,
                                                   short* __restrict__ out) {
    size_t i = ((size_t)blockIdx.x * 256 + threadIdx.x) * 4;
    float4v v = *(const float4v*)(in + i);
    short4v o; o.x = f2bf(v.x); o.y = f2bf(v.y); o.z = f2bf(v.z); o.w = f2bf(v.w);
    *(short4v*)(out + i) = o;
}

// ---------------------------------------------------------------------------
// All 4 weight transposes in ONE launch. fp32 [K=2048][N] -> bf16 [N][2048].
// grid (80, 32): bx<32 Wq | <40 Wk | <48 Wv | else Wo.
// ---------------------------------------------------------------------------
__global__ __launch_bounds__(256) void transpose_all_kernel(const float* __restrict__ Wq,
                                                            const float* __restrict__ Wk,
                                                            const float* __restrict__ Wv,
                                                            const float* __restrict__ Wo,
                                                            short* __restrict__ Wt,
                                                            short* __restrict__ Wot) {
    __shared__ float tile[64][65];
    const int bx = blockIdx.x, by = blockIdx.y;
    const float* src; short* dst; int N, nb;
    if (bx < 32)      { src = Wq; dst = Wt;                         N = 2048; nb = bx; }
    else if (bx < 40) { src = Wk; dst = Wt + (size_t)KOFF_ * 2048;  N = 512;  nb = bx - 32; }
    else if (bx < 48) { src = Wv; dst = Wt + (size_t)VOFF_ * 2048;  N = 512;  nb = bx - 40; }
    else              { src = Wo; dst = Wot;                        N = 2048; nb = bx - 48; }
    const int n0 = nb * 64, k0 = by * 64;
    const int tid = threadIdx.x;
    for (int r = 0; r < 16; ++r) {
        int k = r * 4 + (tid >> 6);
        int n = tid & 63;
        tile[k][n] = src[(size_t)(k0 + k) * N + n0 + n];
    }
    __syncthreads();
    for (int r = 0; r < 4; ++r) {
        int n  = r * 16 + (tid >> 4);
        int kk = (tid & 15) * 4;
        short4v o4;
        o4.x = f2bf(tile[kk + 0][n]); o4.y = f2bf(tile[kk + 1][n]);
        o4.z = f2bf(tile[kk + 2][n]); o4.w = f2bf(tile[kk + 3][n]);
        *(short4v*)&dst[(size_t)(n0 + n) * 2048 + k0 + kk] = o4;
    }
}

// ---------------------------------------------------------------------------
// m97-style GEMM (used for O-proj): C[M][N] = A[M][K] @ Bt[N][K]^T, fp32 out.
// ---------------------------------------------------------------------------
template<typename TC>
__global__ __launch_bounds__(256) void gemm_tt_kernel(const short* __restrict__ A,
                                                      const short* __restrict__ Bt,
                                                      TC* __restrict__ C,
                                                      int M, int N, int K) {
    __shared__ short As[128 * 32];
    __shared__ short Bs[128 * 32];

    const int tid  = threadIdx.x;
    const int bn   = blockIdx.x, bm = blockIdx.y;
    const int wave = tid >> 6, lane = tid & 63;
    const int quad = lane >> 4, l16 = lane & 15;
    const int wr = wave >> 1, wc = wave & 1;

    f32x4 acc[4][4];
    for (int i = 0; i < 4; ++i)
        for (int j = 0; j < 4; ++j) acc[i][j] = (f32x4){0.f, 0.f, 0.f, 0.f};

    const short* Abase = A  + (size_t)(bm * 128) * K;
    const short* Bbase = Bt + (size_t)(bn * 128) * K;

    int ci0 = wave * 128 + lane;
    for (int k0 = 0; k0 < K; k0 += 32) {
        __syncthreads();
        for (int t = 0; t < 2; ++t) {
            int ci = ci0 + t * 64;
            int r  = ci >> 2;
            int c  = ((ci & 3) - (r >> 1)) & 3;
            size_t goff = (size_t)r * K + k0 + c * 8;
            async16(Abase + goff, &As[ci * 8]);
            async16(Bbase + goff, &Bs[ci * 8]);
        }
        __syncthreads();

        bf16x8 af[4], bfv[4];
        for (int mt = 0; mt < 4; ++mt) {
            int r = wr * 64 + mt * 16 + l16;
            af[mt] = *(const bf16x8*)&As[r * 32 + (((quad + (r >> 1)) & 3) * 8)];
        }
        for (int nt = 0; nt < 4; ++nt) {
            int r = wc * 64 + nt * 16 + l16;
            bfv[nt] = *(const bf16x8*)&Bs[r * 32 + (((quad + (r >> 1)) & 3) * 8)];
        }
        for (int mt = 0; mt < 4; ++mt)
            for (int nt = 0; nt < 4; ++nt)
                acc[mt][nt] = __builtin_amdgcn_mfma_f32_16x16x32_bf16(
                    af[mt], bfv[nt], acc[mt][nt], 0, 0, 0);
    }

    for (int mt = 0; mt < 4; ++mt)
        for (int nt = 0; nt < 4; ++nt)
            for (int j = 0; j < 4; ++j) {
                int row = bm * 128 + wr * 64 + mt * 16 + quad * 4 + j;
                int col = bn * 128 + wc * 64 + nt * 16 + l16;
                float v = acc[mt][nt][j];
                if constexpr (__is_same(TC, short))
                    C[(size_t)row * N + col] = f2bf(v);
                else
                    C[(size_t)row * N + col] = v;
            }
}

// ---------------------------------------------------------------------------
// Fused QKV GEMM + RMSNorm + RoPE + V-transpose — 256x256 8-phase schedule.
// C = xb[4096][2048] @ Wt[3072][2048]^T, tile 256x256, BK=64, 512 thr (8 waves
// as 2Mx4N, each wave owns a 128x64 sub-tile). grid (12, 16), XCD-swizzled.
//
// Staging order (deepened pipeline, r2): each half-tile is staged the phase
// after its buffer's last ds_read, giving >=3 phases of slack before its
// vmcnt.  Steady state: ph1:A1h1 | ph3:B0h0' | ph4:B0h1'+A0h0', vmcnt(6) |
// ph5:A0h1' | ph7:B1h0' | ph8:B1h1'+A1h0'', vmcnt(6).  6-7 halves in flight.
// ---------------------------------------------------------------------------
#define QKV_ITERS 16   // K=2048 / (2 K-tiles * 64)

__global__ __launch_bounds__(512, 2) void qkv_fused_kernel(const short* __restrict__ xb,
                                                           const short* __restrict__ Wt,
                                                           const float* __restrict__ cosb,
                                                           const float* __restrict__ sinb,
                                                           const float* __restrict__ qw,
                                                           const float* __restrict__ kw,
                                                           short* __restrict__ q_rope,
                                                           short* __restrict__ k_rope,
                                                           short* __restrict__ vtr) {
    __shared__ __align__(16) short smem[65536];   // 128KB: A0|A1|B0|B1, then C tile
    __shared__ float ss2[4][256];                 // per-row sumsq per wc group

    short* A0 = smem;
    short* A1 = smem + 16384;
    short* B0 = smem + 32768;
    short* B1 = smem + 49152;

    const int tid  = threadIdx.x;
    // XCD-aware swizzle: 192 blocks, all co-resident; give each XCD 24
    // consecutive linear ids = 2 bm rows x 12 bn -> A panels L2-resident.
    const int orig = blockIdx.y * 12 + blockIdx.x;
    const int swz  = (orig & 7) * 24 + (orig >> 3);
    const int bn = swz % 12, bm = swz / 12;
    const int wave = tid >> 6, lane = tid & 63;
    const int quad = lane >> 4, l16 = lane & 15;
    const int wr = wave >> 2, wc = wave & 3;      // 2M x 4N waves

    const short* Ag = xb + (size_t)(bm * 256) * 2048;
    const short* Bg = Wt + (size_t)(bn * 256) * 2048;

    f32x4 acc[8][4];
#pragma unroll
    for (int i = 0; i < 8; ++i)
#pragma unroll
        for (int j = 0; j < 4; ++j) acc[i][j] = (f32x4){0.f, 0.f, 0.f, 0.f};

    bf16x8 a[4][2], b0[2][2], b1[2][2];

    // stage one half-tile (128 rows x 64 k) of a 256x64 slot; LDS dest linear,
    // global source inverse-swizzled so swizzled ds_reads return true data.
    auto stage_half = [&](const short* gpanel, int t, int h, short* lslot) {
#pragma unroll
        for (int u = 0; u < 2; ++u) {
            int ci = u * 512 + tid;                 // 0..1023
            int r  = ci >> 3;                       // 0..127
            int cb = ((ci & 7) * 16) ^ ((r & 7) << 4);
            async16(gpanel + (size_t)(h * 128 + r) * 2048 + t * 64 + (cb >> 1),
                    lslot + h * 8192 + ci * 8);
        }
    };

#define LDA_(lbuf, qm) \
    _Pragma("unroll") for (int mt = 0; mt < 4; ++mt) \
    _Pragma("unroll") for (int ks = 0; ks < 2; ++ks) { \
        int row_ = wr * 128 + (qm) * 64 + mt * 16 + l16; \
        int cb_  = (ks * 64 + quad * 16) ^ ((row_ & 7) << 4); \
        a[mt][ks] = *(const bf16x8*)&(lbuf)[row_ * 64 + (cb_ >> 1)]; \
    }
#define LDB_(lbuf, qn, breg) \
    _Pragma("unroll") for (int ntl = 0; ntl < 2; ++ntl) \
    _Pragma("unroll") for (int ks = 0; ks < 2; ++ks) { \
        int row_ = wc * 64 + (qn) * 32 + ntl * 16 + l16; \
        int cb_  = (ks * 64 + quad * 16) ^ ((row_ & 7) << 4); \
        breg[ntl][ks] = *(const bf16x8*)&(lbuf)[row_ * 64 + (cb_ >> 1)]; \
    }
#define MFMA16_(qm, qn, breg) \
    _Pragma("unroll") for (int mt = 0; mt < 4; ++mt) \
    _Pragma("unroll") for (int ntl = 0; ntl < 2; ++ntl) \
    _Pragma("unroll") for (int ks = 0; ks < 2; ++ks) \
        acc[(qm) * 4 + mt][(qn) * 2 + ntl] = __builtin_amdgcn_mfma_f32_16x16x32_bf16( \
            a[mt][ks], breg[ntl][ks], acc[(qm) * 4 + mt][(qn) * 2 + ntl], 0, 0, 0);
#define PH_BAR() do { __builtin_amdgcn_sched_barrier(0); __builtin_amdgcn_s_barrier(); } while (0)
#define PH_MFMA(qm, qn, breg) do { \
        __builtin_amdgcn_s_setprio(1); MFMA16_(qm, qn, breg); __builtin_amdgcn_s_setprio(0); \
        __builtin_amdgcn_sched_barrier(0); __builtin_amdgcn_s_barrier(); } while (0)

    // prologue: 7 halves in flight: B0(t0), A0(t0), B1(t1), A1(t1)h0.
    // vmcnt(6) drains B0,A0 (phases 1-4's data); leftover = B1h0,B1h1,A1h0.
    stage_half(Bg, 0, 0, B0); stage_half(Bg, 0, 1, B0);
    stage_half(Ag, 0, 0, A0); stage_half(Ag, 0, 1, A0);
    stage_half(Bg, 1, 0, B1); stage_half(Bg, 1, 1, B1);
    stage_half(Ag, 1, 0, A1);
    asm volatile("s_waitcnt vmcnt(6)" ::: "memory");
    __builtin_amdgcn_s_barrier();

#pragma unroll 1
    for (int i = 0; i < QKV_ITERS; ++i) {
        const int tE = 2 * i, tO = 2 * i + 1;
        const bool more = (i < QKV_ITERS - 1);
        // ---- phases 1-4: tile tE from buf0 ----
        LDA_(A0, 0); LDB_(B0, 0, b0);
        stage_half(Ag, tO, 1, A1);                 // A1h1 (h0 staged last ph8)
        PH_BAR(); PH_MFMA(0, 0, b0);

        LDB_(B0, 1, b1);
        PH_BAR(); PH_MFMA(0, 1, b1);

        LDA_(A0, 1);
        if (more) stage_half(Bg, tE + 2, 0, B0);   // B0 last read ph2 -> safe
        PH_BAR(); PH_MFMA(1, 0, b0);

        if (more) {
            stage_half(Bg, tE + 2, 1, B0);
            stage_half(Ag, tE + 2, 0, A0);         // A0 last read ph3 -> safe
            asm volatile("s_waitcnt vmcnt(6)" ::: "memory");  // A1,B1 done
        } else {
            asm volatile("s_waitcnt vmcnt(0)" ::: "memory");
        }
        PH_BAR(); PH_MFMA(1, 1, b1);

        // ---- phases 5-8: tile tO from buf1 ----
        LDA_(A1, 0); LDB_(B1, 0, b0);
        if (more) stage_half(Ag, tE + 2, 1, A0);
        PH_BAR(); PH_MFMA(0, 0, b0);

        LDB_(B1, 1, b1);
        PH_BAR(); PH_MFMA(0, 1, b1);

        LDA_(A1, 1);
        if (more) stage_half(Bg, tO + 2, 0, B1);   // B1 last read ph6 -> safe
        PH_BAR(); PH_MFMA(1, 0, b0);

        if (more) {
            stage_half(Bg, tO + 2, 1, B1);
            stage_half(Ag, tO + 2, 0, A1);         // A1 last read ph7 -> safe
            asm volatile("s_waitcnt vmcnt(6)" ::: "memory");  // A0',B0' done
        } else {
            asm volatile("s_waitcnt vmcnt(0)" ::: "memory");
        }
        PH_BAR(); PH_MFMA(1, 1, b1);
    }

    // ----------------------- epilogue -----------------------
    if (bn >= 10) {
        // V: direct transposed store, (b,g,d,s), 4-token runs of 8B
        const int gbase = (bn - 10) * 2;
#pragma unroll
        for (int am = 0; am < 8; ++am) {
            int tok0 = bm * 256 + wr * 128 + am * 16 + quad * 4;
            int bb = tok0 >> 11, s0 = tok0 & (S_ - 1);
#pragma unroll
            for (int nt = 0; nt < 4; ++nt) {
                int col = wc * 64 + nt * 16 + l16;
                int g = gbase + (col >> 7);
                int d = col & 127;
                short4v o4;
                o4.x = f2bf(acc[am][nt][0]); o4.y = f2bf(acc[am][nt][1]);
                o4.z = f2bf(acc[am][nt][2]); o4.w = f2bf(acc[am][nt][3]);
                *(short4v*)&vtr[((size_t)(bb * NKV_ + g) * HD_ + d) * S_ + s0] = o4;
            }
        }
        return;
    }

    // Q/K: per-row sumsq (per 64-col wave group) + bf16 C tile into LDS
    {
        float pss[8][4];
#pragma unroll
        for (int am = 0; am < 8; ++am)
#pragma unroll
            for (int j = 0; j < 4; ++j) {
                float s = 0.f;
#pragma unroll
                for (int nt = 0; nt < 4; ++nt) s += acc[am][nt][j] * acc[am][nt][j];
                pss[am][j] = s;
            }
#pragma unroll
        for (int off = 1; off < 16; off <<= 1)
#pragma unroll
            for (int am = 0; am < 8; ++am)
#pragma unroll
                for (int j = 0; j < 4; ++j)
                    pss[am][j] += __shfl_xor(pss[am][j], off);
        if (l16 == 0)
#pragma unroll
            for (int am = 0; am < 8; ++am)
#pragma unroll
                for (int j = 0; j < 4; ++j)
                    ss2[wc][wr * 128 + am * 16 + quad * 4 + j] = pss[am][j];
    }
    short* ct = smem;   // 256x256 bf16 C tile (overlays staging buffers)
#pragma unroll
    for (int am = 0; am < 8; ++am)
#pragma unroll
        for (int nt = 0; nt < 4; ++nt)
#pragma unroll
            for (int j = 0; j < 4; ++j)
                ct[(wr * 128 + am * 16 + quad * 4 + j) * 256 + wc * 64 + nt * 16 + l16]
                    = f2bf(acc[am][nt][j]);
    __syncthreads();

    const bool isQ = (bn < 8);
    const float osc = isQ ? (SCALE_ * LOG2E_) : 1.0f;
    const float* w = isQ ? qw : kw;
#pragma unroll 1
    for (int it = 0; it < 16; ++it) {
        int idx = it * 512 + tid;          // 0..8191
        int row = idx >> 5;
        int s32 = idx & 31;
        int head = s32 >> 4, seg = s32 & 15;
        int tok = bm * 256 + row;
        int bb = tok >> 11, s = tok & (S_ - 1);
        float rstd = rsqrtf((ss2[2 * head][row] + ss2[2 * head + 1][row]) * (1.0f / HD_) + EPS_);
        int c0 = seg * 8, p0 = (seg ^ 8) * 8;
        bf16x8 ta = *(const bf16x8*)&ct[row * 256 + head * 128 + c0];
        bf16x8 tb = *(const bf16x8*)&ct[row * 256 + head * 128 + p0];
        float sgn = (seg < 8) ? -1.0f : 1.0f;
        float4v cs0 = *(const float4v*)&cosb[(size_t)s * HD_ + c0];
        float4v cs1 = *(const float4v*)&cosb[(size_t)s * HD_ + c0 + 4];
        float4v sn0 = *(const float4v*)&sinb[(size_t)s * HD_ + c0];
        float4v sn1 = *(const float4v*)&sinb[(size_t)s * HD_ + c0 + 4];
        float ov[8];
#pragma unroll
        for (int i = 0; i < 8; ++i) {
            float n1 = bf2f(ta[i]) * rstd * w[c0 + i];
            float n2 = bf2f(tb[i]) * rstd * w[p0 + i];
            float cs = (i < 4) ? cs0[i & 3] : cs1[i & 3];
            float sn = (i < 4) ? sn0[i & 3] : sn1[i & 3];
            ov[i] = (n1 * cs + sgn * n2 * sn) * osc;
        }
        uint4v wv;
#pragma unroll
        for (int i2 = 0; i2 < 4; ++i2)
            wv[i2] = ((unsigned)(unsigned short)f2bf(ov[2 * i2])) |
                     ((unsigned)(unsigned short)f2bf(ov[2 * i2 + 1]) << 16);
        int gh = isQ ? (bn * 2 + head) : ((bn - 8) * 2 + head);
        short* dst = isQ
            ? q_rope + ((size_t)(bb * S_ + s) * NH_ + gh) * HD_ + c0
            : k_rope + ((size_t)(bb * NKV_ + gh) * S_ + s) * HD_ + c0;
        *(uint4v*)dst = wv;
    }
#undef LDA_
#undef LDB_
#undef MFMA16_
#undef PH_BAR
#undef PH_MFMA
}

// ---------------------------------------------------------------------------
// Flash causal GQA attention v4 (+ setprio around MFMA clusters, r2).
// ---------------------------------------------------------------------------
__global__ __launch_bounds__(256, 2) void attn_kernel(const short* __restrict__ qr,
                                                      const short* __restrict__ kg,
                                                      const short* __restrict__ vt,
                                                      short* __restrict__ aout) {
    __shared__ short Ks[2][64 * 128];
    __shared__ short Vs[2][128 * 64];

    const int lin = blockIdx.x;
    const int b  = lin & 1;
    const int g  = (lin >> 1) & 3;
    const int hq = (lin >> 3) & 3;
    const int pr = lin >> 5;
    const int h  = g * 4 + hq;

    const int wave = threadIdx.x >> 6, lane = threadIdx.x & 63;
    const int quad = lane >> 4, l16 = lane & 15;

    const short* kbase = kg + (size_t)(b * NKV_ + g) * S_ * HD_;
    const short* vbase = vt + (size_t)(b * NKV_ + g) * HD_ * S_;

    for (int pass = 0; pass < 2; ++pass) {
        const int qt    = pass ? (31 - pr) : pr;
        const int iters = qt + 1;
        const int qrow  = qt * 64 + wave * 16 + l16;

        bf16x8 qf[4];
        {
            const short* qp = qr + ((size_t)(b * S_ + qrow) * NH_ + h) * HD_;
            for (int ks = 0; ks < 4; ++ks)
                qf[ks] = *(const bf16x8*)(qp + ks * 32 + quad * 8);
        }

        f32x4 o[8];
        for (int i = 0; i < 8; ++i) o[i] = (f32x4){0.f, 0.f, 0.f, 0.f};
        float m_i = -INFINITY, l_i = 0.f;

        auto stage = [&](int kt, int bsel) {
            const short* kt_base = kbase + (size_t)kt * 64 * HD_;
            const short* vt_base = vbase + kt * 64;
            for (int t = 0; t < 4; ++t) {
                int ci  = (wave * 4 + t) * 64 + lane;
                int key = ci >> 4;
                int c   = (ci & 15) ^ ((key ^ (key >> 2)) & 15);
                async16(kt_base + key * HD_ + c * 8, &Ks[bsel][ci * 8]);
            }
            for (int t = 0; t < 4; ++t) {
                int ci = (wave * 4 + t) * 64 + lane;
                int d  = ci >> 3;
                int c  = (ci & 7) ^ (d & 7);
                async16(vt_base + (size_t)d * S_ + c * 8, &Vs[bsel][ci * 8]);
            }
        };

        stage(0, 0);
        int buf = 0;
        for (int kt = 0; kt < iters; ++kt) {
            __syncthreads();
            if (kt + 1 < iters) stage(kt + 1, buf ^ 1);

            f32x4 acc[4];
            for (int t = 0; t < 4; ++t) acc[t] = (f32x4){0.f, 0.f, 0.f, 0.f};
            __builtin_amdgcn_s_setprio(1);
            for (int t = 0; t < 4; ++t) {
                int lk = ((t >> 1) << 5) + ((l16 >> 2) << 3) + ((t & 1) << 2) + (l16 & 3);
                const short* kp = &Ks[buf][lk * 128];
                int pm = (lk ^ (lk >> 2)) & 15;
                for (int ks = 0; ks < 4; ++ks) {
                    bf16x8 kf = *(const bf16x8*)(kp + (((ks * 4 + quad) ^ pm) * 8));
                    acc[t] = __builtin_amdgcn_mfma_f32_16x16x32_bf16(kf, qf[ks], acc[t], 0, 0, 0);
                }
            }
            __builtin_amdgcn_s_setprio(0);
            const int key_base = kt * 64;
            if (key_base + 63 > qt * 64 + wave * 16) {
                for (int t = 0; t < 4; ++t)
                    for (int j = 0; j < 4; ++j) {
                        int kl = key_base + ((t >> 1) << 5) + (quad << 3) + ((t & 1) << 2) + j;
                        if (kl > qrow) acc[t][j] = -INFINITY;
                    }
            }
            float mx = m_i;
            for (int t = 0; t < 4; ++t)
                for (int j = 0; j < 4; ++j) mx = fmaxf(mx, acc[t][j]);
            mx = fmaxf(mx, __shfl_xor(mx, 16));
            mx = fmaxf(mx, __shfl_xor(mx, 32));
            float al = __builtin_amdgcn_exp2f(m_i - mx);
            m_i = mx;
            float rs = 0.f;
            float p[4][4];
            for (int t = 0; t < 4; ++t)
                for (int j = 0; j < 4; ++j) {
                    float e = __builtin_amdgcn_exp2f(acc[t][j] - mx);
                    p[t][j] = e;
                    rs += e;
                }
            rs += __shfl_xor(rs, 16);
            rs += __shfl_xor(rs, 32);
            l_i = al * l_i + rs;
            for (int d8 = 0; d8 < 8; ++d8)
                for (int j = 0; j < 4; ++j) o[d8][j] *= al;
            unsigned pk[2][4];
            for (int grp = 0; grp < 2; ++grp) {
                pk[grp][0] = pack_bf2(p[2 * grp][0],     p[2 * grp][1]);
                pk[grp][1] = pack_bf2(p[2 * grp][2],     p[2 * grp][3]);
                pk[grp][2] = pack_bf2(p[2 * grp + 1][0], p[2 * grp + 1][1]);
                pk[grp][3] = pack_bf2(p[2 * grp + 1][2], p[2 * grp + 1][3]);
            }
            __builtin_amdgcn_s_setprio(1);
            for (int grp = 0; grp < 2; ++grp) {
                union { unsigned u[4]; bf16x8 v; } pb;
                for (int i = 0; i < 4; ++i) pb.u[i] = pk[grp][i];
                for (int d8 = 0; d8 < 8; ++d8) {
                    int d = d8 * 16 + l16;
                    bf16x8 vf = *(const bf16x8*)&Vs[buf][d * 64 + (((grp * 4 + quad) ^ (d & 7)) * 8)];
                    o[d8] = __builtin_amdgcn_mfma_f32_16x16x32_bf16(vf, pb.v, o[d8], 0, 0, 0);
                }
            }
            __builtin_amdgcn_s_setprio(0);
            buf ^= 1;
        }
        float il = 1.0f / l_i;
        short* op = aout + ((size_t)(b * S_ + qrow) * NH_ + h) * HD_ + quad * 4;
        for (int d8 = 0; d8 < 8; ++d8) {
            uint2v wv;
            wv.x = ((unsigned)(unsigned short)f2bf(o[d8][0] * il)) |
                   ((unsigned)(unsigned short)f2bf(o[d8][1] * il) << 16);
            wv.y = ((unsigned)(unsigned short)f2bf(o[d8][2] * il)) |
                   ((unsigned)(unsigned short)f2bf(o[d8][3] * il) << 16);
            *(uint2v*)(op + d8 * 16) = wv;
        }
        __syncthreads();
    }
}

// ---------------------------------------------------------------------------
extern "C" void kernel_launch(void* const* d_in, const int* in_sizes, int n_in,
                              void* d_out, int out_size, void* d_ws, size_t ws_size,
                              hipStream_t stream) {
    (void)in_sizes; (void)n_in; (void)out_size; (void)ws_size;
    const float* x    = (const float*)d_in[0];
    const float* cosb = (const float*)d_in[1];
    const float* sinb = (const float*)d_in[2];
    const float* Wq   = (const float*)d_in[3];
    const float* Wk   = (const float*)d_in[4];
    const float* Wv   = (const float*)d_in[5];
    const float* Wo   = (const float*)d_in[6];
    const float* qw   = (const float*)d_in[7];
    const float* kw   = (const float*)d_in[8];
    float* out = (float*)d_out;

    char* ws = (char*)d_ws;
    short* xb     = (short*)ws;  ws += (size_t)4096 * 2048 * 2;    // 16MB
    short* Wt     = (short*)ws;  ws += (size_t)3072 * 2048 * 2;    // 12MB [n][k]
    short* Wot    = (short*)ws;  ws += (size_t)2048 * 2048 * 2;    // 8MB  [n][k]
    short* q_rope = (short*)ws;  ws += (size_t)4096 * 2048 * 2;    // 16MB (b,s,h,hd)
    short* k_rope = (short*)ws;  ws += (size_t)4096 * 512 * 2;     // 4MB  (b,g,s,hd)
    short* vt     = (short*)ws;  ws += (size_t)4096 * 512 * 2;     // 4MB  (b,g,hd,s)
    short* a_out  = (short*)ws;  ws += (size_t)4096 * 2048 * 2;    // 16MB

    const int M = B_ * S_;  // 4096

    // pre-pass: x cast + all weight transposes
    cast_kernel<<<M * 2048 / 1024, 256, 0, stream>>>(x, xb);
    transpose_all_kernel<<<dim3(80, 32), 256, 0, stream>>>(Wq, Wk, Wv, Wo, Wt, Wot);

    // fused QKV projection + RMSNorm + RoPE + V transpose (256^2 8-phase)
    qkv_fused_kernel<<<dim3(12, M / 256), 512, 0, stream>>>(
        xb, Wt, cosb, sinb, qw, kw, q_rope, k_rope, vt);

    // causal GQA flash attention: 512 equal blocks x 256 threads, 2 blocks/CU
    attn_kernel<<<512, 256, 0, stream>>>(q_rope, k_rope, vt, a_out);

    // output projection: [4096][2048] @ [2048][2048] -> fp32 out
    gemm_tt_kernel<float><<<dim3(D_ / 128, M / 128), 256, 0, stream>>>(
        a_out, Wot, out, M, D_, 2048);
}

// Round 3
// 304.225 us; speedup vs baseline: 1.0714x; 1.0100x over previous
//
#include <hip/hip_runtime.h>
#include <hip/hip_bf16.h>
#include <math.h>

#define B_ 2
#define S_ 2048
#define D_ 2048
#define NH_ 16
#define NKV_ 4
#define HD_ 128
#define EPS_ 1e-6f
#define SCALE_ 0.08838834764831845f  // 1/sqrt(128)
#define LOG2E_ 1.4426950408889634f
#define KOFF_ 2048                   // k rows offset in fused Wt
#define VOFF_ 2560                   // v rows offset in fused Wt

typedef float f32x4 __attribute__((ext_vector_type(4)));
typedef short bf16x8 __attribute__((ext_vector_type(8)));
typedef short short4v __attribute__((ext_vector_type(4)));
typedef float float4v __attribute__((ext_vector_type(4)));
typedef unsigned uint2v __attribute__((ext_vector_type(2)));
typedef unsigned uint4v __attribute__((ext_vector_type(4)));

static __device__ __forceinline__ short f2bf(float f) {
    union { float f; unsigned u; } x{f};
    unsigned r = (x.u + 0x7fff + ((x.u >> 16) & 1)) >> 16;   // RTNE
    return (short)r;
}
static __device__ __forceinline__ float bf2f(short s) {
    union { unsigned u; float f; } x; x.u = ((unsigned)(unsigned short)s) << 16; return x.f;
}
// pack two fp32 -> two bf16 (truncation) in ONE v_perm: lo16=hi16(a), hi16=hi16(b)
static __device__ __forceinline__ unsigned pack_bf2(float a, float b) {
    return __builtin_amdgcn_perm(__builtin_bit_cast(unsigned, b),
                                 __builtin_bit_cast(unsigned, a), 0x07060302u);
}

#define AS1(p) ((const __attribute__((address_space(1))) void*)(p))
#define AS3(p) ((__attribute__((address_space(3))) void*)(p))
static __device__ __forceinline__ void async16(const void* g, void* l) {
    __builtin_amdgcn_global_load_lds(AS1(g), AS3(l), 16, 0, 0);
}

// ---------------------------------------------------------------------------
// fp32 -> bf16 flat cast (for x). 4 elems/thread.
// ---------------------------------------------------------------------------
__global__ __launch_bounds__(256) void cast_kernel(const float* __restrict__ in,
                                                   short* __restrict__ out) {
    size_t i = ((size_t)blockIdx.x * 256 + threadIdx.x) * 4;
    float4v v = *(const float4v*)(in + i);
    short4v o; o.x = f2bf(v.x); o.y = f2bf(v.y); o.z = f2bf(v.z); o.w = f2bf(v.w);
    *(short4v*)(out + i) = o;
}

// ---------------------------------------------------------------------------
// All 4 weight transposes in ONE launch. fp32 [K=2048][N] -> bf16 [N][2048].
// grid (80, 32): bx<32 Wq | <40 Wk | <48 Wv | else Wo.
// ---------------------------------------------------------------------------
__global__ __launch_bounds__(256) void transpose_all_kernel(const float* __restrict__ Wq,
                                                            const float* __restrict__ Wk,
                                                            const float* __restrict__ Wv,
                                                            const float* __restrict__ Wo,
                                                            short* __restrict__ Wt,
                                                            short* __restrict__ Wot) {
    __shared__ float tile[64][65];
    const int bx = blockIdx.x, by = blockIdx.y;
    const float* src; short* dst; int N, nb;
    if (bx < 32)      { src = Wq; dst = Wt;                         N = 2048; nb = bx; }
    else if (bx < 40) { src = Wk; dst = Wt + (size_t)KOFF_ * 2048;  N = 512;  nb = bx - 32; }
    else if (bx < 48) { src = Wv; dst = Wt + (size_t)VOFF_ * 2048;  N = 512;  nb = bx - 40; }
    else              { src = Wo; dst = Wot;                        N = 2048; nb = bx - 48; }
    const int n0 = nb * 64, k0 = by * 64;
    const int tid = threadIdx.x;
    for (int r = 0; r < 16; ++r) {
        int k = r * 4 + (tid >> 6);
        int n = tid & 63;
        tile[k][n] = src[(size_t)(k0 + k) * N + n0 + n];
    }
    __syncthreads();
    for (int r = 0; r < 4; ++r) {
        int n  = r * 16 + (tid >> 4);
        int kk = (tid & 15) * 4;
        short4v o4;
        o4.x = f2bf(tile[kk + 0][n]); o4.y = f2bf(tile[kk + 1][n]);
        o4.z = f2bf(tile[kk + 2][n]); o4.w = f2bf(tile[kk + 3][n]);
        *(short4v*)&dst[(size_t)(n0 + n) * 2048 + k0 + kk] = o4;
    }
}

// ---------------------------------------------------------------------------
// m97-style GEMM (used for O-proj): C[M][N] = A[M][K] @ Bt[N][K]^T, fp32 out.
// ---------------------------------------------------------------------------
template<typename TC>
__global__ __launch_bounds__(256) void gemm_tt_kernel(const short* __restrict__ A,
                                                      const short* __restrict__ Bt,
                                                      TC* __restrict__ C,
                                                      int M, int N, int K) {
    __shared__ short As[128 * 32];
    __shared__ short Bs[128 * 32];

    const int tid  = threadIdx.x;
    const int bn   = blockIdx.x, bm = blockIdx.y;
    const int wave = tid >> 6, lane = tid & 63;
    const int quad = lane >> 4, l16 = lane & 15;
    const int wr = wave >> 1, wc = wave & 1;

    f32x4 acc[4][4];
    for (int i = 0; i < 4; ++i)
        for (int j = 0; j < 4; ++j) acc[i][j] = (f32x4){0.f, 0.f, 0.f, 0.f};

    const short* Abase = A  + (size_t)(bm * 128) * K;
    const short* Bbase = Bt + (size_t)(bn * 128) * K;

    int ci0 = wave * 128 + lane;
    for (int k0 = 0; k0 < K; k0 += 32) {
        __syncthreads();
        for (int t = 0; t < 2; ++t) {
            int ci = ci0 + t * 64;
            int r  = ci >> 2;
            int c  = ((ci & 3) - (r >> 1)) & 3;
            size_t goff = (size_t)r * K + k0 + c * 8;
            async16(Abase + goff, &As[ci * 8]);
            async16(Bbase + goff, &Bs[ci * 8]);
        }
        __syncthreads();

        bf16x8 af[4], bfv[4];
        for (int mt = 0; mt < 4; ++mt) {
            int r = wr * 64 + mt * 16 + l16;
            af[mt] = *(const bf16x8*)&As[r * 32 + (((quad + (r >> 1)) & 3) * 8)];
        }
        for (int nt = 0; nt < 4; ++nt) {
            int r = wc * 64 + nt * 16 + l16;
            bfv[nt] = *(const bf16x8*)&Bs[r * 32 + (((quad + (r >> 1)) & 3) * 8)];
        }
        for (int mt = 0; mt < 4; ++mt)
            for (int nt = 0; nt < 4; ++nt)
                acc[mt][nt] = __builtin_amdgcn_mfma_f32_16x16x32_bf16(
                    af[mt], bfv[nt], acc[mt][nt], 0, 0, 0);
    }

    for (int mt = 0; mt < 4; ++mt)
        for (int nt = 0; nt < 4; ++nt)
            for (int j = 0; j < 4; ++j) {
                int row = bm * 128 + wr * 64 + mt * 16 + quad * 4 + j;
                int col = bn * 128 + wc * 64 + nt * 16 + l16;
                float v = acc[mt][nt][j];
                if constexpr (__is_same(TC, short))
                    C[(size_t)row * N + col] = f2bf(v);
                else
                    C[(size_t)row * N + col] = v;
            }
}

// ---------------------------------------------------------------------------
// Fused QKV GEMM + RMSNorm + RoPE + V-transpose — 256x256, 4-phase schedule.
// C = xb[4096][2048] @ Wt[3072][2048]^T, tile 256x256, BK=64, 512 thr (8 waves
// as 2Mx4N, each wave owns a 128x64 sub-tile). grid (12, 16), XCD-swizzled.
//
// r3: merged 8 phases -> 4 phases per 2 K-tiles (32-MFMA clusters) to halve
// barrier count (was ~1200 cyc/K-tile of sync overhead). Staging schedule
// (each half-tile restaged >=1 barrier after its last read):
//   P1: read A0q0,B0(b0+b1); stage A1(tO) h0+h1;            MFMA(0,*) tE
//   P2: read A0q1;           stage B0(tE+2) h0+h1; vmcnt(4) MFMA(1,*) tE
//   P3: read A1q0,B1(b0+b1); stage A0(tE+2) h0+h1;          MFMA(0,*) tO
//   P4: read A1q1;           stage B1(tO+2) h0+h1; vmcnt(4) MFMA(1,*) tO
// vmcnt(4) at P2 drains A1(tO),B1(tO) for P3; at P4 drains B0,A0(tE+2) for
// next P1. Never 0 in steady state; last iteration drains with vmcnt(0).
// ---------------------------------------------------------------------------
#define QKV_ITERS 16   // K=2048 / (2 K-tiles * 64)

__global__ __launch_bounds__(512, 2) void qkv_fused_kernel(const short* __restrict__ xb,
                                                           const short* __restrict__ Wt,
                                                           const float* __restrict__ cosb,
                                                           const float* __restrict__ sinb,
                                                           const float* __restrict__ qw,
                                                           const float* __restrict__ kw,
                                                           short* __restrict__ q_rope,
                                                           short* __restrict__ k_rope,
                                                           short* __restrict__ vtr) {
    __shared__ __align__(16) short smem[65536];   // 128KB: A0|A1|B0|B1, then C tile
    __shared__ float ss2[4][256];                 // per-row sumsq per wc group

    short* A0 = smem;
    short* A1 = smem + 16384;
    short* B0 = smem + 32768;
    short* B1 = smem + 49152;

    const int tid  = threadIdx.x;
    // XCD-aware swizzle: 192 blocks, all co-resident; give each XCD 24
    // consecutive linear ids = 2 bm rows x 12 bn -> A panels L2-resident.
    const int orig = blockIdx.y * 12 + blockIdx.x;
    const int swz  = (orig & 7) * 24 + (orig >> 3);
    const int bn = swz % 12, bm = swz / 12;
    const int wave = tid >> 6, lane = tid & 63;
    const int quad = lane >> 4, l16 = lane & 15;
    const int wr = wave >> 2, wc = wave & 3;      // 2M x 4N waves

    const short* Ag = xb + (size_t)(bm * 256) * 2048;
    const short* Bg = Wt + (size_t)(bn * 256) * 2048;

    f32x4 acc[8][4];
#pragma unroll
    for (int i = 0; i < 8; ++i)
#pragma unroll
        for (int j = 0; j < 4; ++j) acc[i][j] = (f32x4){0.f, 0.f, 0.f, 0.f};

    bf16x8 a[4][2], b0[2][2], b1[2][2];

    // stage one half-tile (128 rows x 64 k) of a 256x64 slot; LDS dest linear,
    // global source inverse-swizzled so swizzled ds_reads return true data.
    auto stage_half = [&](const short* gpanel, int t, int h, short* lslot) {
#pragma unroll
        for (int u = 0; u < 2; ++u) {
            int ci = u * 512 + tid;                 // 0..1023
            int r  = ci >> 3;                       // 0..127
            int cb = ((ci & 7) * 16) ^ ((r & 7) << 4);
            async16(gpanel + (size_t)(h * 128 + r) * 2048 + t * 64 + (cb >> 1),
                    lslot + h * 8192 + ci * 8);
        }
    };

#define LDA_(lbuf, qm) \
    _Pragma("unroll") for (int mt = 0; mt < 4; ++mt) \
    _Pragma("unroll") for (int ks = 0; ks < 2; ++ks) { \
        int row_ = wr * 128 + (qm) * 64 + mt * 16 + l16; \
        int cb_  = (ks * 64 + quad * 16) ^ ((row_ & 7) << 4); \
        a[mt][ks] = *(const bf16x8*)&(lbuf)[row_ * 64 + (cb_ >> 1)]; \
    }
#define LDB_(lbuf, qn, breg) \
    _Pragma("unroll") for (int ntl = 0; ntl < 2; ++ntl) \
    _Pragma("unroll") for (int ks = 0; ks < 2; ++ks) { \
        int row_ = wc * 64 + (qn) * 32 + ntl * 16 + l16; \
        int cb_  = (ks * 64 + quad * 16) ^ ((row_ & 7) << 4); \
        breg[ntl][ks] = *(const bf16x8*)&(lbuf)[row_ * 64 + (cb_ >> 1)]; \
    }
#define MFMA16_(qm, qn, breg) \
    _Pragma("unroll") for (int mt = 0; mt < 4; ++mt) \
    _Pragma("unroll") for (int ntl = 0; ntl < 2; ++ntl) \
    _Pragma("unroll") for (int ks = 0; ks < 2; ++ks) \
        acc[(qm) * 4 + mt][(qn) * 2 + ntl] = __builtin_amdgcn_mfma_f32_16x16x32_bf16( \
            a[mt][ks], breg[ntl][ks], acc[(qm) * 4 + mt][(qn) * 2 + ntl], 0, 0, 0);
#define PH_BAR() do { __builtin_amdgcn_sched_barrier(0); __builtin_amdgcn_s_barrier(); } while (0)
#define PH_MFMA2(qm) do { \
        __builtin_amdgcn_s_setprio(1); MFMA16_(qm, 0, b0); MFMA16_(qm, 1, b1); \
        __builtin_amdgcn_s_setprio(0); \
        __builtin_amdgcn_sched_barrier(0); __builtin_amdgcn_s_barrier(); } while (0)

    // prologue: B0(t0), A0(t0), B1(t1) = 12 ops; vmcnt(4) leaves B1 in flight
    stage_half(Bg, 0, 0, B0); stage_half(Bg, 0, 1, B0);
    stage_half(Ag, 0, 0, A0); stage_half(Ag, 0, 1, A0);
    stage_half(Bg, 1, 0, B1); stage_half(Bg, 1, 1, B1);
    asm volatile("s_waitcnt vmcnt(4)" ::: "memory");
    __builtin_amdgcn_s_barrier();

#pragma unroll 1
    for (int i = 0; i < QKV_ITERS; ++i) {
        const int tE = 2 * i, tO = 2 * i + 1;
        const bool more = (i < QKV_ITERS - 1);

        // ---- P1: tile tE, row-quadrant 0 ----
        LDA_(A0, 0); LDB_(B0, 0, b0); LDB_(B0, 1, b1);
        stage_half(Ag, tO, 0, A1); stage_half(Ag, tO, 1, A1);   // A1 last read prev P4
        PH_BAR();
        PH_MFMA2(0);

        // ---- P2: tile tE, row-quadrant 1 ----
        LDA_(A0, 1);
        if (more) {
            stage_half(Bg, tE + 2, 0, B0); stage_half(Bg, tE + 2, 1, B0);  // B0 last read P1
            asm volatile("s_waitcnt vmcnt(4)" ::: "memory");   // A1(tO),B1(tO) ready
        } else {
            asm volatile("s_waitcnt vmcnt(0)" ::: "memory");
        }
        PH_BAR();
        PH_MFMA2(1);

        // ---- P3: tile tO, row-quadrant 0 ----
        LDA_(A1, 0); LDB_(B1, 0, b0); LDB_(B1, 1, b1);
        if (more) { stage_half(Ag, tE + 2, 0, A0); stage_half(Ag, tE + 2, 1, A0); } // A0 read P1/P2
        PH_BAR();
        PH_MFMA2(0);

        // ---- P4: tile tO, row-quadrant 1 ----
        LDA_(A1, 1);
        if (more) {
            stage_half(Bg, tO + 2, 0, B1); stage_half(Bg, tO + 2, 1, B1);  // B1 last read P3
            asm volatile("s_waitcnt vmcnt(4)" ::: "memory");   // B0,A0(tE+2) ready
        }
        PH_BAR();
        PH_MFMA2(1);
    }

    // ----------------------- epilogue -----------------------
    if (bn >= 10) {
        // V: direct transposed store, (b,g,d,s), 4-token runs of 8B
        const int gbase = (bn - 10) * 2;
#pragma unroll
        for (int am = 0; am < 8; ++am) {
            int tok0 = bm * 256 + wr * 128 + am * 16 + quad * 4;
            int bb = tok0 >> 11, s0 = tok0 & (S_ - 1);
#pragma unroll
            for (int nt = 0; nt < 4; ++nt) {
                int col = wc * 64 + nt * 16 + l16;
                int g = gbase + (col >> 7);
                int d = col & 127;
                short4v o4;
                o4.x = f2bf(acc[am][nt][0]); o4.y = f2bf(acc[am][nt][1]);
                o4.z = f2bf(acc[am][nt][2]); o4.w = f2bf(acc[am][nt][3]);
                *(short4v*)&vtr[((size_t)(bb * NKV_ + g) * HD_ + d) * S_ + s0] = o4;
            }
        }
        return;
    }

    // Q/K: per-row sumsq (per 64-col wave group) + bf16 C tile into LDS
    {
        float pss[8][4];
#pragma unroll
        for (int am = 0; am < 8; ++am)
#pragma unroll
            for (int j = 0; j < 4; ++j) {
                float s = 0.f;
#pragma unroll
                for (int nt = 0; nt < 4; ++nt) s += acc[am][nt][j] * acc[am][nt][j];
                pss[am][j] = s;
            }
#pragma unroll
        for (int off = 1; off < 16; off <<= 1)
#pragma unroll
            for (int am = 0; am < 8; ++am)
#pragma unroll
                for (int j = 0; j < 4; ++j)
                    pss[am][j] += __shfl_xor(pss[am][j], off);
        if (l16 == 0)
#pragma unroll
            for (int am = 0; am < 8; ++am)
#pragma unroll
                for (int j = 0; j < 4; ++j)
                    ss2[wc][wr * 128 + am * 16 + quad * 4 + j] = pss[am][j];
    }
    short* ct = smem;   // 256x256 bf16 C tile (overlays staging buffers)
#pragma unroll
    for (int am = 0; am < 8; ++am)
#pragma unroll
        for (int nt = 0; nt < 4; ++nt)
#pragma unroll
            for (int j = 0; j < 4; ++j)
                ct[(wr * 128 + am * 16 + quad * 4 + j) * 256 + wc * 64 + nt * 16 + l16]
                    = f2bf(acc[am][nt][j]);
    __syncthreads();

    const bool isQ = (bn < 8);
    const float osc = isQ ? (SCALE_ * LOG2E_) : 1.0f;
    const float* w = isQ ? qw : kw;
#pragma unroll 1
    for (int it = 0; it < 16; ++it) {
        int idx = it * 512 + tid;          // 0..8191
        int row = idx >> 5;
        int s32 = idx & 31;
        int head = s32 >> 4, seg = s32 & 15;
        int tok = bm * 256 + row;
        int bb = tok >> 11, s = tok & (S_ - 1);
        float rstd = rsqrtf((ss2[2 * head][row] + ss2[2 * head + 1][row]) * (1.0f / HD_) + EPS_);
        int c0 = seg * 8, p0 = (seg ^ 8) * 8;
        bf16x8 ta = *(const bf16x8*)&ct[row * 256 + head * 128 + c0];
        bf16x8 tb = *(const bf16x8*)&ct[row * 256 + head * 128 + p0];
        float sgn = (seg < 8) ? -1.0f : 1.0f;
        float4v cs0 = *(const float4v*)&cosb[(size_t)s * HD_ + c0];
        float4v cs1 = *(const float4v*)&cosb[(size_t)s * HD_ + c0 + 4];
        float4v sn0 = *(const float4v*)&sinb[(size_t)s * HD_ + c0];
        float4v sn1 = *(const float4v*)&sinb[(size_t)s * HD_ + c0 + 4];
        float ov[8];
#pragma unroll
        for (int i = 0; i < 8; ++i) {
            float n1 = bf2f(ta[i]) * rstd * w[c0 + i];
            float n2 = bf2f(tb[i]) * rstd * w[p0 + i];
            float cs = (i < 4) ? cs0[i & 3] : cs1[i & 3];
            float sn = (i < 4) ? sn0[i & 3] : sn1[i & 3];
            ov[i] = (n1 * cs + sgn * n2 * sn) * osc;
        }
        uint4v wv;
#pragma unroll
        for (int i2 = 0; i2 < 4; ++i2)
            wv[i2] = ((unsigned)(unsigned short)f2bf(ov[2 * i2])) |
                     ((unsigned)(unsigned short)f2bf(ov[2 * i2 + 1]) << 16);
        int gh = isQ ? (bn * 2 + head) : ((bn - 8) * 2 + head);
        short* dst = isQ
            ? q_rope + ((size_t)(bb * S_ + s) * NH_ + gh) * HD_ + c0
            : k_rope + ((size_t)(bb * NKV_ + gh) * S_ + s) * HD_ + c0;
        *(uint4v*)dst = wv;
    }
#undef LDA_
#undef LDB_
#undef MFMA16_
#undef PH_BAR
#undef PH_MFMA2
}

// ---------------------------------------------------------------------------
// Flash causal GQA attention v4 (+ setprio around MFMA clusters).
// ---------------------------------------------------------------------------
__global__ __launch_bounds__(256, 2) void attn_kernel(const short* __restrict__ qr,
                                                      const short* __restrict__ kg,
                                                      const short* __restrict__ vt,
                                                      short* __restrict__ aout) {
    __shared__ short Ks[2][64 * 128];
    __shared__ short Vs[2][128 * 64];

    const int lin = blockIdx.x;
    const int b  = lin & 1;
    const int g  = (lin >> 1) & 3;
    const int hq = (lin >> 3) & 3;
    const int pr = lin >> 5;
    const int h  = g * 4 + hq;

    const int wave = threadIdx.x >> 6, lane = threadIdx.x & 63;
    const int quad = lane >> 4, l16 = lane & 15;

    const short* kbase = kg + (size_t)(b * NKV_ + g) * S_ * HD_;
    const short* vbase = vt + (size_t)(b * NKV_ + g) * HD_ * S_;

    for (int pass = 0; pass < 2; ++pass) {
        const int qt    = pass ? (31 - pr) : pr;
        const int iters = qt + 1;
        const int qrow  = qt * 64 + wave * 16 + l16;

        bf16x8 qf[4];
        {
            const short* qp = qr + ((size_t)(b * S_ + qrow) * NH_ + h) * HD_;
            for (int ks = 0; ks < 4; ++ks)
                qf[ks] = *(const bf16x8*)(qp + ks * 32 + quad * 8);
        }

        f32x4 o[8];
        for (int i = 0; i < 8; ++i) o[i] = (f32x4){0.f, 0.f, 0.f, 0.f};
        float m_i = -INFINITY, l_i = 0.f;

        auto stage = [&](int kt, int bsel) {
            const short* kt_base = kbase + (size_t)kt * 64 * HD_;
            const short* vt_base = vbase + kt * 64;
            for (int t = 0; t < 4; ++t) {
                int ci  = (wave * 4 + t) * 64 + lane;
                int key = ci >> 4;
                int c   = (ci & 15) ^ ((key ^ (key >> 2)) & 15);
                async16(kt_base + key * HD_ + c * 8, &Ks[bsel][ci * 8]);
            }
            for (int t = 0; t < 4; ++t) {
                int ci = (wave * 4 + t) * 64 + lane;
                int d  = ci >> 3;
                int c  = (ci & 7) ^ (d & 7);
                async16(vt_base + (size_t)d * S_ + c * 8, &Vs[bsel][ci * 8]);
            }
        };

        stage(0, 0);
        int buf = 0;
        for (int kt = 0; kt < iters; ++kt) {
            __syncthreads();
            if (kt + 1 < iters) stage(kt + 1, buf ^ 1);

            f32x4 acc[4];
            for (int t = 0; t < 4; ++t) acc[t] = (f32x4){0.f, 0.f, 0.f, 0.f};
            __builtin_amdgcn_s_setprio(1);
            for (int t = 0; t < 4; ++t) {
                int lk = ((t >> 1) << 5) + ((l16 >> 2) << 3) + ((t & 1) << 2) + (l16 & 3);
                const short* kp = &Ks[buf][lk * 128];
                int pm = (lk ^ (lk >> 2)) & 15;
                for (int ks = 0; ks < 4; ++ks) {
                    bf16x8 kf = *(const bf16x8*)(kp + (((ks * 4 + quad) ^ pm) * 8));
                    acc[t] = __builtin_amdgcn_mfma_f32_16x16x32_bf16(kf, qf[ks], acc[t], 0, 0, 0);
                }
            }
            __builtin_amdgcn_s_setprio(0);
            const int key_base = kt * 64;
            if (key_base + 63 > qt * 64 + wave * 16) {
                for (int t = 0; t < 4; ++t)
                    for (int j = 0; j < 4; ++j) {
                        int kl = key_base + ((t >> 1) << 5) + (quad << 3) + ((t & 1) << 2) + j;
                        if (kl > qrow) acc[t][j] = -INFINITY;
                    }
            }
            float mx = m_i;
            for (int t = 0; t < 4; ++t)
                for (int j = 0; j < 4; ++j) mx = fmaxf(mx, acc[t][j]);
            mx = fmaxf(mx, __shfl_xor(mx, 16));
            mx = fmaxf(mx, __shfl_xor(mx, 32));
            float al = __builtin_amdgcn_exp2f(m_i - mx);
            m_i = mx;
            float rs = 0.f;
            float p[4][4];
            for (int t = 0; t < 4; ++t)
                for (int j = 0; j < 4; ++j) {
                    float e = __builtin_amdgcn_exp2f(acc[t][j] - mx);
                    p[t][j] = e;
                    rs += e;
                }
            rs += __shfl_xor(rs, 16);
            rs += __shfl_xor(rs, 32);
            l_i = al * l_i + rs;
            for (int d8 = 0; d8 < 8; ++d8)
                for (int j = 0; j < 4; ++j) o[d8][j] *= al;
            unsigned pk[2][4];
            for (int grp = 0; grp < 2; ++grp) {
                pk[grp][0] = pack_bf2(p[2 * grp][0],     p[2 * grp][1]);
                pk[grp][1] = pack_bf2(p[2 * grp][2],     p[2 * grp][3]);
                pk[grp][2] = pack_bf2(p[2 * grp + 1][0], p[2 * grp + 1][1]);
                pk[grp][3] = pack_bf2(p[2 * grp + 1][2], p[2 * grp + 1][3]);
            }
            __builtin_amdgcn_s_setprio(1);
            for (int grp = 0; grp < 2; ++grp) {
                union { unsigned u[4]; bf16x8 v; } pb;
                for (int i = 0; i < 4; ++i) pb.u[i] = pk[grp][i];
                for (int d8 = 0; d8 < 8; ++d8) {
                    int d = d8 * 16 + l16;
                    bf16x8 vf = *(const bf16x8*)&Vs[buf][d * 64 + (((grp * 4 + quad) ^ (d & 7)) * 8)];
                    o[d8] = __builtin_amdgcn_mfma_f32_16x16x32_bf16(vf, pb.v, o[d8], 0, 0, 0);
                }
            }
            __builtin_amdgcn_s_setprio(0);
            buf ^= 1;
        }
        float il = 1.0f / l_i;
        short* op = aout + ((size_t)(b * S_ + qrow) * NH_ + h) * HD_ + quad * 4;
        for (int d8 = 0; d8 < 8; ++d8) {
            uint2v wv;
            wv.x = ((unsigned)(unsigned short)f2bf(o[d8][0] * il)) |
                   ((unsigned)(unsigned short)f2bf(o[d8][1] * il) << 16);
            wv.y = ((unsigned)(unsigned short)f2bf(o[d8][2] * il)) |
                   ((unsigned)(unsigned short)f2bf(o[d8][3] * il) << 16);
            *(uint2v*)(op + d8 * 16) = wv;
        }
        __syncthreads();
    }
}

// ---------------------------------------------------------------------------
extern "C" void kernel_launch(void* const* d_in, const int* in_sizes, int n_in,
                              void* d_out, int out_size, void* d_ws, size_t ws_size,
                              hipStream_t stream) {
    (void)in_sizes; (void)n_in; (void)out_size; (void)ws_size;
    const float* x    = (const float*)d_in[0];
    const float* cosb = (const float*)d_in[1];
    const float* sinb = (const float*)d_in[2];
    const float* Wq   = (const float*)d_in[3];
    const float* Wk   = (const float*)d_in[4];
    const float* Wv   = (const float*)d_in[5];
    const float* Wo   = (const float*)d_in[6];
    const float* qw   = (const float*)d_in[7];
    const float* kw   = (const float*)d_in[8];
    float* out = (float*)d_out;

    char* ws = (char*)d_ws;
    short* xb     = (short*)ws;  ws += (size_t)4096 * 2048 * 2;    // 16MB
    short* Wt     = (short*)ws;  ws += (size_t)3072 * 2048 * 2;    // 12MB [n][k]
    short* Wot    = (short*)ws;  ws += (size_t)2048 * 2048 * 2;    // 8MB  [n][k]
    short* q_rope = (short*)ws;  ws += (size_t)4096 * 2048 * 2;    // 16MB (b,s,h,hd)
    short* k_rope = (short*)ws;  ws += (size_t)4096 * 512 * 2;     // 4MB  (b,g,s,hd)
    short* vt     = (short*)ws;  ws += (size_t)4096 * 512 * 2;     // 4MB  (b,g,hd,s)
    short* a_out  = (short*)ws;  ws += (size_t)4096 * 2048 * 2;    // 16MB

    const int M = B_ * S_;  // 4096

    // pre-pass: x cast + all weight transposes
    cast_kernel<<<M * 2048 / 1024, 256, 0, stream>>>(x, xb);
    transpose_all_kernel<<<dim3(80, 32), 256, 0, stream>>>(Wq, Wk, Wv, Wo, Wt, Wot);

    // fused QKV projection + RMSNorm + RoPE + V transpose (256^2 4-phase)
    qkv_fused_kernel<<<dim3(12, M / 256), 512, 0, stream>>>(
        xb, Wt, cosb, sinb, qw, kw, q_rope, k_rope, vt);

    // causal GQA flash attention: 512 equal blocks x 256 threads, 2 blocks/CU
    attn_kernel<<<512, 256, 0, stream>>>(q_rope, k_rope, vt, a_out);

    // output projection: [4096][2048] @ [2048][2048] -> fp32 out
    gemm_tt_kernel<float><<<dim3(D_ / 128, M / 128), 256, 0, stream>>>(
        a_out, Wot, out, M, D_, 2048);
}

// Round 4
// 292.634 us; speedup vs baseline: 1.1138x; 1.0396x over previous
//
#include <hip/hip_runtime.h>
#include <hip/hip_bf16.h>
#include <math.h>

#define B_ 2
#define S_ 2048
#define D_ 2048
#define NH_ 16
#define NKV_ 4
#define HD_ 128
#define EPS_ 1e-6f
#define SCALE_ 0.08838834764831845f  // 1/sqrt(128)
#define LOG2E_ 1.4426950408889634f
#define KOFF_ 2048                   // k rows offset in fused Wt
#define VOFF_ 2560                   // v rows offset in fused Wt

typedef float f32x4 __attribute__((ext_vector_type(4)));
typedef short bf16x8 __attribute__((ext_vector_type(8)));
typedef short short4v __attribute__((ext_vector_type(4)));
typedef float float4v __attribute__((ext_vector_type(4)));
typedef unsigned uint2v __attribute__((ext_vector_type(2)));
typedef unsigned uint4v __attribute__((ext_vector_type(4)));

static __device__ __forceinline__ short f2bf(float f) {
    union { float f; unsigned u; } x{f};
    unsigned r = (x.u + 0x7fff + ((x.u >> 16) & 1)) >> 16;   // RTNE
    return (short)r;
}
static __device__ __forceinline__ float bf2f(short s) {
    union { unsigned u; float f; } x; x.u = ((unsigned)(unsigned short)s) << 16; return x.f;
}
// pack two fp32 -> two bf16 (truncation) in ONE v_perm: lo16=hi16(a), hi16=hi16(b)
static __device__ __forceinline__ unsigned pack_bf2(float a, float b) {
    return __builtin_amdgcn_perm(__builtin_bit_cast(unsigned, b),
                                 __builtin_bit_cast(unsigned, a), 0x07060302u);
}

#define AS1(p) ((const __attribute__((address_space(1))) void*)(p))
#define AS3(p) ((__attribute__((address_space(3))) void*)(p))
static __device__ __forceinline__ void async16(const void* g, void* l) {
    __builtin_amdgcn_global_load_lds(AS1(g), AS3(l), 16, 0, 0);
}
#define SB_() __builtin_amdgcn_sched_barrier(0)

// ---------------------------------------------------------------------------
// fp32 -> bf16 flat cast (for x). 4 elems/thread.
// ---------------------------------------------------------------------------
__global__ __launch_bounds__(256) void cast_kernel(const float* __restrict__ in,
                                                   short* __restrict__ out) {
    size_t i = ((size_t)blockIdx.x * 256 + threadIdx.x) * 4;
    float4v v = *(const float4v*)(in + i);
    short4v o; o.x = f2bf(v.x); o.y = f2bf(v.y); o.z = f2bf(v.z); o.w = f2bf(v.w);
    *(short4v*)(out + i) = o;
}

// ---------------------------------------------------------------------------
// All 4 weight transposes in ONE launch. fp32 [K=2048][N] -> bf16 [N][2048].
// grid (80, 32): bx<32 Wq | <40 Wk | <48 Wv | else Wo.
// ---------------------------------------------------------------------------
__global__ __launch_bounds__(256) void transpose_all_kernel(const float* __restrict__ Wq,
                                                            const float* __restrict__ Wk,
                                                            const float* __restrict__ Wv,
                                                            const float* __restrict__ Wo,
                                                            short* __restrict__ Wt,
                                                            short* __restrict__ Wot) {
    __shared__ float tile[64][65];
    const int bx = blockIdx.x, by = blockIdx.y;
    const float* src; short* dst; int N, nb;
    if (bx < 32)      { src = Wq; dst = Wt;                         N = 2048; nb = bx; }
    else if (bx < 40) { src = Wk; dst = Wt + (size_t)KOFF_ * 2048;  N = 512;  nb = bx - 32; }
    else if (bx < 48) { src = Wv; dst = Wt + (size_t)VOFF_ * 2048;  N = 512;  nb = bx - 40; }
    else              { src = Wo; dst = Wot;                        N = 2048; nb = bx - 48; }
    const int n0 = nb * 64, k0 = by * 64;
    const int tid = threadIdx.x;
    for (int r = 0; r < 16; ++r) {
        int k = r * 4 + (tid >> 6);
        int n = tid & 63;
        tile[k][n] = src[(size_t)(k0 + k) * N + n0 + n];
    }
    __syncthreads();
    for (int r = 0; r < 4; ++r) {
        int n  = r * 16 + (tid >> 4);
        int kk = (tid & 15) * 4;
        short4v o4;
        o4.x = f2bf(tile[kk + 0][n]); o4.y = f2bf(tile[kk + 1][n]);
        o4.z = f2bf(tile[kk + 2][n]); o4.w = f2bf(tile[kk + 3][n]);
        *(short4v*)&dst[(size_t)(n0 + n) * 2048 + k0 + kk] = o4;
    }
}

// ---------------------------------------------------------------------------
// O-proj GEMM: C[4096][2048] fp32 = a_out[4096][2048]bf16 @ Wot[2048][2048]^T.
// Tile 128x256, BK=64, 2 K-tiles/iter, 16 iters. grid (8,32) = 256 blocks =
// exactly 1 round on 256 CUs. 8 waves (2M x 4N), wave-tile 64x64.
// LDS 96KB: A[2][128][64] + B[2][256][64], XOR-swizzled reads, counted vmcnt.
// Single barrier per phase (post-MFMA); compiler interleaves reads w/ MFMAs.
// ---------------------------------------------------------------------------
__global__ __launch_bounds__(512, 2) void gemm_oproj_kernel(const short* __restrict__ A,
                                                            const short* __restrict__ Bt,
                                                            float* __restrict__ C) {
    __shared__ __align__(16) short smem[49152];   // 96KB
    short* A0 = smem;            // 128x64
    short* A1 = smem + 8192;
    short* B0 = smem + 16384;    // 256x64
    short* B1 = smem + 32768;

    const int tid  = threadIdx.x;
    const int orig = blockIdx.y * 8 + blockIdx.x;       // 0..255
    const int swz  = (orig & 7) * 32 + (orig >> 3);     // XCD chunking (256%8==0)
    const int bn = swz & 7, bm = swz >> 3;
    const int wave = tid >> 6, lane = tid & 63;
    const int quad = lane >> 4, l16 = lane & 15;
    const int wr = wave >> 2, wc = wave & 3;            // 2M x 4N waves

    const short* Ag = A  + (size_t)(bm * 128) * 2048;
    const short* Bg = Bt + (size_t)(bn * 256) * 2048;

    f32x4 acc[4][4];
#pragma unroll
    for (int i = 0; i < 4; ++i)
#pragma unroll
        for (int j = 0; j < 4; ++j) acc[i][j] = (f32x4){0.f, 0.f, 0.f, 0.f};

    bf16x8 a[4][2], b0[2][2], b1[2][2];

    auto stage_half = [&](const short* gpanel, int t, int h, short* lslot) {
#pragma unroll
        for (int u = 0; u < 2; ++u) {
            int ci = u * 512 + tid;
            int r  = ci >> 3;
            int cb = ((ci & 7) * 16) ^ ((r & 7) << 4);
            async16(gpanel + (size_t)(h * 128 + r) * 2048 + t * 64 + (cb >> 1),
                    lslot + h * 8192 + ci * 8);
        }
    };

#define OLDA_(lbuf) \
    _Pragma("unroll") for (int mt = 0; mt < 4; ++mt) \
    _Pragma("unroll") for (int ks = 0; ks < 2; ++ks) { \
        int row_ = wr * 64 + mt * 16 + l16; \
        int cb_  = (ks * 64 + quad * 16) ^ ((row_ & 7) << 4); \
        a[mt][ks] = *(const bf16x8*)&(lbuf)[row_ * 64 + (cb_ >> 1)]; \
    }
#define OLDB_(lbuf, qn, breg) \
    _Pragma("unroll") for (int ntl = 0; ntl < 2; ++ntl) \
    _Pragma("unroll") for (int ks = 0; ks < 2; ++ks) { \
        int row_ = wc * 64 + (qn) * 32 + ntl * 16 + l16; \
        int cb_  = (ks * 64 + quad * 16) ^ ((row_ & 7) << 4); \
        breg[ntl][ks] = *(const bf16x8*)&(lbuf)[row_ * 64 + (cb_ >> 1)]; \
    }
#define OMFMA_(qn, breg) do { \
    __builtin_amdgcn_s_setprio(1); \
    _Pragma("unroll") for (int mt = 0; mt < 4; ++mt) \
    _Pragma("unroll") for (int ntl = 0; ntl < 2; ++ntl) \
    _Pragma("unroll") for (int ks = 0; ks < 2; ++ks) \
        acc[mt][(qn) * 2 + ntl] = __builtin_amdgcn_mfma_f32_16x16x32_bf16( \
            a[mt][ks], breg[ntl][ks], acc[mt][(qn) * 2 + ntl], 0, 0, 0); \
    __builtin_amdgcn_s_setprio(0); SB_(); __builtin_amdgcn_s_barrier(); } while (0)

    // prologue: B0(t0) 4u + A0(t0) 2u; full drain
    stage_half(Bg, 0, 0, B0); stage_half(Bg, 0, 1, B0);
    stage_half(Ag, 0, 0, A0);
    SB_(); asm volatile("s_waitcnt vmcnt(0)" ::: "memory");
    __builtin_amdgcn_s_barrier();

#pragma unroll 1
    for (int i = 0; i < 16; ++i) {
        const int tE = 2 * i, tO = 2 * i + 1;
        const bool more = (i < 15);

        // P1: stage A1(tO)+B1(tO); read aE, bE-h0; MFMA
        stage_half(Ag, tO, 0, A1);
        stage_half(Bg, tO, 0, B1); stage_half(Bg, tO, 1, B1);
        OLDA_(A0); OLDB_(B0, 0, b0);
        OMFMA_(0, b0);

        // P2: stage A0(tE+2); vmcnt(2) drains A1,B1; read bE-h1; MFMA
        if (more) {
            stage_half(Ag, tE + 2, 0, A0);
            SB_(); asm volatile("s_waitcnt vmcnt(2)" ::: "memory");
        } else {
            SB_(); asm volatile("s_waitcnt vmcnt(0)" ::: "memory");
        }
        OLDB_(B0, 1, b1);
        OMFMA_(1, b1);

        // P3: stage B0(tE+2); read aO, bO-h0; MFMA
        if (more) { stage_half(Bg, tE + 2, 0, B0); stage_half(Bg, tE + 2, 1, B0); }
        OLDA_(A1); OLDB_(B1, 0, b0);
        OMFMA_(0, b0);

        // P4: vmcnt(0) drains A0',B0' for next P1; read bO-h1; MFMA
        if (more) { SB_(); asm volatile("s_waitcnt vmcnt(0)" ::: "memory"); }
        OLDB_(B1, 1, b1);
        OMFMA_(1, b1);
    }

    // epilogue: direct fp32 store
#pragma unroll
    for (int mt = 0; mt < 4; ++mt)
#pragma unroll
        for (int nt = 0; nt < 4; ++nt)
#pragma unroll
            for (int j = 0; j < 4; ++j) {
                int row = bm * 128 + wr * 64 + mt * 16 + quad * 4 + j;
                int col = bn * 256 + wc * 64 + nt * 16 + l16;
                C[(size_t)row * 2048 + col] = acc[mt][nt][j];
            }
#undef OLDA_
#undef OLDB_
#undef OMFMA_
}

// ---------------------------------------------------------------------------
// Fused QKV GEMM + RMSNorm + RoPE + V-transpose — 256x256, 4-phase, 1 barrier
// per phase (r4). grid (12, 16), XCD-swizzled. Staging schedule as r3:
//   P1: stage A1(tO)       | read aE-q0, bE(all) | MFMA(0)
//   P2: stage B0(tE+2), vmcnt(4) | read aE-q1    | MFMA(1)
//   P3: stage A0(tE+2)     | read aO-q0, bO(all) | MFMA(0)
//   P4: stage B1(tO+2), vmcnt(4) | read aO-q1    | MFMA(1)
// Barrier only AFTER each MFMA cluster: all reads complete before it (lgkm
// precedes use), so staging issued next phase is WAR-safe; vmcnt asm with
// memory clobber separates every stage from its first reader.
// ---------------------------------------------------------------------------
#define QKV_ITERS 16   // K=2048 / (2 K-tiles * 64)

__global__ __launch_bounds__(512, 2) void qkv_fused_kernel(const short* __restrict__ xb,
                                                           const short* __restrict__ Wt,
                                                           const float* __restrict__ cosb,
                                                           const float* __restrict__ sinb,
                                                           const float* __restrict__ qw,
                                                           const float* __restrict__ kw,
                                                           short* __restrict__ q_rope,
                                                           short* __restrict__ k_rope,
                                                           short* __restrict__ vtr) {
    __shared__ __align__(16) short smem[65536];   // 128KB: A0|A1|B0|B1, then C tile
    __shared__ float ss2[4][256];                 // per-row sumsq per wc group

    short* A0 = smem;
    short* A1 = smem + 16384;
    short* B0 = smem + 32768;
    short* B1 = smem + 49152;

    const int tid  = threadIdx.x;
    const int orig = blockIdx.y * 12 + blockIdx.x;
    const int swz  = (orig & 7) * 24 + (orig >> 3);
    const int bn = swz % 12, bm = swz / 12;
    const int wave = tid >> 6, lane = tid & 63;
    const int quad = lane >> 4, l16 = lane & 15;
    const int wr = wave >> 2, wc = wave & 3;      // 2M x 4N waves

    const short* Ag = xb + (size_t)(bm * 256) * 2048;
    const short* Bg = Wt + (size_t)(bn * 256) * 2048;

    f32x4 acc[8][4];
#pragma unroll
    for (int i = 0; i < 8; ++i)
#pragma unroll
        for (int j = 0; j < 4; ++j) acc[i][j] = (f32x4){0.f, 0.f, 0.f, 0.f};

    bf16x8 a[4][2], b0[2][2], b1[2][2];

    auto stage_half = [&](const short* gpanel, int t, int h, short* lslot) {
#pragma unroll
        for (int u = 0; u < 2; ++u) {
            int ci = u * 512 + tid;                 // 0..1023
            int r  = ci >> 3;                       // 0..127
            int cb = ((ci & 7) * 16) ^ ((r & 7) << 4);
            async16(gpanel + (size_t)(h * 128 + r) * 2048 + t * 64 + (cb >> 1),
                    lslot + h * 8192 + ci * 8);
        }
    };

#define LDA_(lbuf, qm) \
    _Pragma("unroll") for (int mt = 0; mt < 4; ++mt) \
    _Pragma("unroll") for (int ks = 0; ks < 2; ++ks) { \
        int row_ = wr * 128 + (qm) * 64 + mt * 16 + l16; \
        int cb_  = (ks * 64 + quad * 16) ^ ((row_ & 7) << 4); \
        a[mt][ks] = *(const bf16x8*)&(lbuf)[row_ * 64 + (cb_ >> 1)]; \
    }
#define LDB_(lbuf, qn, breg) \
    _Pragma("unroll") for (int ntl = 0; ntl < 2; ++ntl) \
    _Pragma("unroll") for (int ks = 0; ks < 2; ++ks) { \
        int row_ = wc * 64 + (qn) * 32 + ntl * 16 + l16; \
        int cb_  = (ks * 64 + quad * 16) ^ ((row_ & 7) << 4); \
        breg[ntl][ks] = *(const bf16x8*)&(lbuf)[row_ * 64 + (cb_ >> 1)]; \
    }
#define MFMA16_(qm, qn, breg) \
    _Pragma("unroll") for (int mt = 0; mt < 4; ++mt) \
    _Pragma("unroll") for (int ntl = 0; ntl < 2; ++ntl) \
    _Pragma("unroll") for (int ks = 0; ks < 2; ++ks) \
        acc[(qm) * 4 + mt][(qn) * 2 + ntl] = __builtin_amdgcn_mfma_f32_16x16x32_bf16( \
            a[mt][ks], breg[ntl][ks], acc[(qm) * 4 + mt][(qn) * 2 + ntl], 0, 0, 0);
#define PH_MFMA2_(qm) do { \
        __builtin_amdgcn_s_setprio(1); MFMA16_(qm, 0, b0); MFMA16_(qm, 1, b1); \
        __builtin_amdgcn_s_setprio(0); SB_(); __builtin_amdgcn_s_barrier(); } while (0)

    // prologue: B0(t0), A0(t0), B1(t1) = 12u; vmcnt(4) leaves B1 in flight
    stage_half(Bg, 0, 0, B0); stage_half(Bg, 0, 1, B0);
    stage_half(Ag, 0, 0, A0); stage_half(Ag, 0, 1, A0);
    stage_half(Bg, 1, 0, B1); stage_half(Bg, 1, 1, B1);
    SB_(); asm volatile("s_waitcnt vmcnt(4)" ::: "memory");
    __builtin_amdgcn_s_barrier();

#pragma unroll 1
    for (int i = 0; i < QKV_ITERS; ++i) {
        const int tE = 2 * i, tO = 2 * i + 1;
        const bool more = (i < QKV_ITERS - 1);

        // P1: stage A1(tO); read aE-q0 + bE; MFMA
        stage_half(Ag, tO, 0, A1); stage_half(Ag, tO, 1, A1);
        LDA_(A0, 0); LDB_(B0, 0, b0); LDB_(B0, 1, b1);
        PH_MFMA2_(0);

        // P2: stage B0(tE+2); vmcnt(4) drains A1,B1(tO); read aE-q1; MFMA
        if (more) {
            stage_half(Bg, tE + 2, 0, B0); stage_half(Bg, tE + 2, 1, B0);
            SB_(); asm volatile("s_waitcnt vmcnt(4)" ::: "memory");
        } else {
            SB_(); asm volatile("s_waitcnt vmcnt(0)" ::: "memory");
        }
        LDA_(A0, 1);
        PH_MFMA2_(1);

        // P3: stage A0(tE+2); read aO-q0 + bO; MFMA
        if (more) { stage_half(Ag, tE + 2, 0, A0); stage_half(Ag, tE + 2, 1, A0); }
        LDA_(A1, 0); LDB_(B1, 0, b0); LDB_(B1, 1, b1);
        PH_MFMA2_(0);

        // P4: stage B1(tO+2); vmcnt(4) drains B0',A0'(tE+2); read aO-q1; MFMA
        if (more) {
            stage_half(Bg, tO + 2, 0, B1); stage_half(Bg, tO + 2, 1, B1);
            SB_(); asm volatile("s_waitcnt vmcnt(4)" ::: "memory");
        }
        LDA_(A1, 1);
        PH_MFMA2_(1);
    }

    // ----------------------- epilogue -----------------------
    if (bn >= 10) {
        // V: direct transposed store, (b,g,d,s), 4-token runs of 8B
        const int gbase = (bn - 10) * 2;
#pragma unroll
        for (int am = 0; am < 8; ++am) {
            int tok0 = bm * 256 + wr * 128 + am * 16 + quad * 4;
            int bb = tok0 >> 11, s0 = tok0 & (S_ - 1);
#pragma unroll
            for (int nt = 0; nt < 4; ++nt) {
                int col = wc * 64 + nt * 16 + l16;
                int g = gbase + (col >> 7);
                int d = col & 127;
                short4v o4;
                o4.x = f2bf(acc[am][nt][0]); o4.y = f2bf(acc[am][nt][1]);
                o4.z = f2bf(acc[am][nt][2]); o4.w = f2bf(acc[am][nt][3]);
                *(short4v*)&vtr[((size_t)(bb * NKV_ + g) * HD_ + d) * S_ + s0] = o4;
            }
        }
        return;
    }

    // Q/K: per-row sumsq (per 64-col wave group) + bf16 C tile into LDS
    {
        float pss[8][4];
#pragma unroll
        for (int am = 0; am < 8; ++am)
#pragma unroll
            for (int j = 0; j < 4; ++j) {
                float s = 0.f;
#pragma unroll
                for (int nt = 0; nt < 4; ++nt) s += acc[am][nt][j] * acc[am][nt][j];
                pss[am][j] = s;
            }
#pragma unroll
        for (int off = 1; off < 16; off <<= 1)
#pragma unroll
            for (int am = 0; am < 8; ++am)
#pragma unroll
                for (int j = 0; j < 4; ++j)
                    pss[am][j] += __shfl_xor(pss[am][j], off);
        if (l16 == 0)
#pragma unroll
            for (int am = 0; am < 8; ++am)
#pragma unroll
                for (int j = 0; j < 4; ++j)
                    ss2[wc][wr * 128 + am * 16 + quad * 4 + j] = pss[am][j];
    }
    short* ct = smem;   // 256x256 bf16 C tile (overlays staging buffers)
#pragma unroll
    for (int am = 0; am < 8; ++am)
#pragma unroll
        for (int nt = 0; nt < 4; ++nt)
#pragma unroll
            for (int j = 0; j < 4; ++j)
                ct[(wr * 128 + am * 16 + quad * 4 + j) * 256 + wc * 64 + nt * 16 + l16]
                    = f2bf(acc[am][nt][j]);
    __syncthreads();

    const bool isQ = (bn < 8);
    const float osc = isQ ? (SCALE_ * LOG2E_) : 1.0f;
    const float* w = isQ ? qw : kw;
#pragma unroll 1
    for (int it = 0; it < 16; ++it) {
        int idx = it * 512 + tid;          // 0..8191
        int row = idx >> 5;
        int s32 = idx & 31;
        int head = s32 >> 4, seg = s32 & 15;
        int tok = bm * 256 + row;
        int bb = tok >> 11, s = tok & (S_ - 1);
        float rstd = rsqrtf((ss2[2 * head][row] + ss2[2 * head + 1][row]) * (1.0f / HD_) + EPS_);
        int c0 = seg * 8, p0 = (seg ^ 8) * 8;
        bf16x8 ta = *(const bf16x8*)&ct[row * 256 + head * 128 + c0];
        bf16x8 tb = *(const bf16x8*)&ct[row * 256 + head * 128 + p0];
        float sgn = (seg < 8) ? -1.0f : 1.0f;
        float4v cs0 = *(const float4v*)&cosb[(size_t)s * HD_ + c0];
        float4v cs1 = *(const float4v*)&cosb[(size_t)s * HD_ + c0 + 4];
        float4v sn0 = *(const float4v*)&sinb[(size_t)s * HD_ + c0];
        float4v sn1 = *(const float4v*)&sinb[(size_t)s * HD_ + c0 + 4];
        float ov[8];
#pragma unroll
        for (int i = 0; i < 8; ++i) {
            float n1 = bf2f(ta[i]) * rstd * w[c0 + i];
            float n2 = bf2f(tb[i]) * rstd * w[p0 + i];
            float cs = (i < 4) ? cs0[i & 3] : cs1[i & 3];
            float sn = (i < 4) ? sn0[i & 3] : sn1[i & 3];
            ov[i] = (n1 * cs + sgn * n2 * sn) * osc;
        }
        uint4v wv;
#pragma unroll
        for (int i2 = 0; i2 < 4; ++i2)
            wv[i2] = ((unsigned)(unsigned short)f2bf(ov[2 * i2])) |
                     ((unsigned)(unsigned short)f2bf(ov[2 * i2 + 1]) << 16);
        int gh = isQ ? (bn * 2 + head) : ((bn - 8) * 2 + head);
        short* dst = isQ
            ? q_rope + ((size_t)(bb * S_ + s) * NH_ + gh) * HD_ + c0
            : k_rope + ((size_t)(bb * NKV_ + gh) * S_ + s) * HD_ + c0;
        *(uint4v*)dst = wv;
    }
#undef LDA_
#undef LDB_
#undef MFMA16_
#undef PH_MFMA2_
}

// ---------------------------------------------------------------------------
// Flash causal GQA attention v4 (+ setprio around MFMA clusters).
// ---------------------------------------------------------------------------
__global__ __launch_bounds__(256, 2) void attn_kernel(const short* __restrict__ qr,
                                                      const short* __restrict__ kg,
                                                      const short* __restrict__ vt,
                                                      short* __restrict__ aout) {
    __shared__ short Ks[2][64 * 128];
    __shared__ short Vs[2][128 * 64];

    const int lin = blockIdx.x;
    const int b  = lin & 1;
    const int g  = (lin >> 1) & 3;
    const int hq = (lin >> 3) & 3;
    const int pr = lin >> 5;
    const int h  = g * 4 + hq;

    const int wave = threadIdx.x >> 6, lane = threadIdx.x & 63;
    const int quad = lane >> 4, l16 = lane & 15;

    const short* kbase = kg + (size_t)(b * NKV_ + g) * S_ * HD_;
    const short* vbase = vt + (size_t)(b * NKV_ + g) * HD_ * S_;

    for (int pass = 0; pass < 2; ++pass) {
        const int qt    = pass ? (31 - pr) : pr;
        const int iters = qt + 1;
        const int qrow  = qt * 64 + wave * 16 + l16;

        bf16x8 qf[4];
        {
            const short* qp = qr + ((size_t)(b * S_ + qrow) * NH_ + h) * HD_;
            for (int ks = 0; ks < 4; ++ks)
                qf[ks] = *(const bf16x8*)(qp + ks * 32 + quad * 8);
        }

        f32x4 o[8];
        for (int i = 0; i < 8; ++i) o[i] = (f32x4){0.f, 0.f, 0.f, 0.f};
        float m_i = -INFINITY, l_i = 0.f;

        auto stage = [&](int kt, int bsel) {
            const short* kt_base = kbase + (size_t)kt * 64 * HD_;
            const short* vt_base = vbase + kt * 64;
            for (int t = 0; t < 4; ++t) {
                int ci  = (wave * 4 + t) * 64 + lane;
                int key = ci >> 4;
                int c   = (ci & 15) ^ ((key ^ (key >> 2)) & 15);
                async16(kt_base + key * HD_ + c * 8, &Ks[bsel][ci * 8]);
            }
            for (int t = 0; t < 4; ++t) {
                int ci = (wave * 4 + t) * 64 + lane;
                int d  = ci >> 3;
                int c  = (ci & 7) ^ (d & 7);
                async16(vt_base + (size_t)d * S_ + c * 8, &Vs[bsel][ci * 8]);
            }
        };

        stage(0, 0);
        int buf = 0;
        for (int kt = 0; kt < iters; ++kt) {
            __syncthreads();
            if (kt + 1 < iters) stage(kt + 1, buf ^ 1);

            f32x4 acc[4];
            for (int t = 0; t < 4; ++t) acc[t] = (f32x4){0.f, 0.f, 0.f, 0.f};
            __builtin_amdgcn_s_setprio(1);
            for (int t = 0; t < 4; ++t) {
                int lk = ((t >> 1) << 5) + ((l16 >> 2) << 3) + ((t & 1) << 2) + (l16 & 3);
                const short* kp = &Ks[buf][lk * 128];
                int pm = (lk ^ (lk >> 2)) & 15;
                for (int ks = 0; ks < 4; ++ks) {
                    bf16x8 kf = *(const bf16x8*)(kp + (((ks * 4 + quad) ^ pm) * 8));
                    acc[t] = __builtin_amdgcn_mfma_f32_16x16x32_bf16(kf, qf[ks], acc[t], 0, 0, 0);
                }
            }
            __builtin_amdgcn_s_setprio(0);
            const int key_base = kt * 64;
            if (key_base + 63 > qt * 64 + wave * 16) {
                for (int t = 0; t < 4; ++t)
                    for (int j = 0; j < 4; ++j) {
                        int kl = key_base + ((t >> 1) << 5) + (quad << 3) + ((t & 1) << 2) + j;
                        if (kl > qrow) acc[t][j] = -INFINITY;
                    }
            }
            float mx = m_i;
            for (int t = 0; t < 4; ++t)
                for (int j = 0; j < 4; ++j) mx = fmaxf(mx, acc[t][j]);
            mx = fmaxf(mx, __shfl_xor(mx, 16));
            mx = fmaxf(mx, __shfl_xor(mx, 32));
            float al = __builtin_amdgcn_exp2f(m_i - mx);
            m_i = mx;
            float rs = 0.f;
            float p[4][4];
            for (int t = 0; t < 4; ++t)
                for (int j = 0; j < 4; ++j) {
                    float e = __builtin_amdgcn_exp2f(acc[t][j] - mx);
                    p[t][j] = e;
                    rs += e;
                }
            rs += __shfl_xor(rs, 16);
            rs += __shfl_xor(rs, 32);
            l_i = al * l_i + rs;
            for (int d8 = 0; d8 < 8; ++d8)
                for (int j = 0; j < 4; ++j) o[d8][j] *= al;
            unsigned pk[2][4];
            for (int grp = 0; grp < 2; ++grp) {
                pk[grp][0] = pack_bf2(p[2 * grp][0],     p[2 * grp][1]);
                pk[grp][1] = pack_bf2(p[2 * grp][2],     p[2 * grp][3]);
                pk[grp][2] = pack_bf2(p[2 * grp + 1][0], p[2 * grp + 1][1]);
                pk[grp][3] = pack_bf2(p[2 * grp + 1][2], p[2 * grp + 1][3]);
            }
            __builtin_amdgcn_s_setprio(1);
            for (int grp = 0; grp < 2; ++grp) {
                union { unsigned u[4]; bf16x8 v; } pb;
                for (int i = 0; i < 4; ++i) pb.u[i] = pk[grp][i];
                for (int d8 = 0; d8 < 8; ++d8) {
                    int d = d8 * 16 + l16;
                    bf16x8 vf = *(const bf16x8*)&Vs[buf][d * 64 + (((grp * 4 + quad) ^ (d & 7)) * 8)];
                    o[d8] = __builtin_amdgcn_mfma_f32_16x16x32_bf16(vf, pb.v, o[d8], 0, 0, 0);
                }
            }
            __builtin_amdgcn_s_setprio(0);
            buf ^= 1;
        }
        float il = 1.0f / l_i;
        short* op = aout + ((size_t)(b * S_ + qrow) * NH_ + h) * HD_ + quad * 4;
        for (int d8 = 0; d8 < 8; ++d8) {
            uint2v wv;
            wv.x = ((unsigned)(unsigned short)f2bf(o[d8][0] * il)) |
                   ((unsigned)(unsigned short)f2bf(o[d8][1] * il) << 16);
            wv.y = ((unsigned)(unsigned short)f2bf(o[d8][2] * il)) |
                   ((unsigned)(unsigned short)f2bf(o[d8][3] * il) << 16);
            *(uint2v*)(op + d8 * 16) = wv;
        }
        __syncthreads();
    }
}

// ---------------------------------------------------------------------------
extern "C" void kernel_launch(void* const* d_in, const int* in_sizes, int n_in,
                              void* d_out, int out_size, void* d_ws, size_t ws_size,
                              hipStream_t stream) {
    (void)in_sizes; (void)n_in; (void)out_size; (void)ws_size;
    const float* x    = (const float*)d_in[0];
    const float* cosb = (const float*)d_in[1];
    const float* sinb = (const float*)d_in[2];
    const float* Wq   = (const float*)d_in[3];
    const float* Wk   = (const float*)d_in[4];
    const float* Wv   = (const float*)d_in[5];
    const float* Wo   = (const float*)d_in[6];
    const float* qw   = (const float*)d_in[7];
    const float* kw   = (const float*)d_in[8];
    float* out = (float*)d_out;

    char* ws = (char*)d_ws;
    short* xb     = (short*)ws;  ws += (size_t)4096 * 2048 * 2;    // 16MB
    short* Wt     = (short*)ws;  ws += (size_t)3072 * 2048 * 2;    // 12MB [n][k]
    short* Wot    = (short*)ws;  ws += (size_t)2048 * 2048 * 2;    // 8MB  [n][k]
    short* q_rope = (short*)ws;  ws += (size_t)4096 * 2048 * 2;    // 16MB (b,s,h,hd)
    short* k_rope = (short*)ws;  ws += (size_t)4096 * 512 * 2;     // 4MB  (b,g,s,hd)
    short* vt     = (short*)ws;  ws += (size_t)4096 * 512 * 2;     // 4MB  (b,g,hd,s)
    short* a_out  = (short*)ws;  ws += (size_t)4096 * 2048 * 2;    // 16MB

    const int M = B_ * S_;  // 4096

    // pre-pass: x cast + all weight transposes
    cast_kernel<<<M * 2048 / 1024, 256, 0, stream>>>(x, xb);
    transpose_all_kernel<<<dim3(80, 32), 256, 0, stream>>>(Wq, Wk, Wv, Wo, Wt, Wot);

    // fused QKV projection + RMSNorm + RoPE + V transpose (256^2, 1-bar phases)
    qkv_fused_kernel<<<dim3(12, M / 256), 512, 0, stream>>>(
        xb, Wt, cosb, sinb, qw, kw, q_rope, k_rope, vt);

    // causal GQA flash attention: 512 equal blocks x 256 threads, 2 blocks/CU
    attn_kernel<<<512, 256, 0, stream>>>(q_rope, k_rope, vt, a_out);

    // output projection: 128x256-tile phase engine, 256 blocks = full machine
    gemm_oproj_kernel<<<dim3(8, 32), 512, 0, stream>>>(a_out, Wot, out);
}